// Round 11
// baseline (411.384 us; speedup 1.0000x reference)
//
#include <hip/hip_runtime.h>
#include <hip/hip_bf16.h>
#include <hip/hip_fp8.h>
#include <math.h>

#define UCNT 50000
#define ICNT 25000
#define NNODE 75000
#define DDIM 64
#define BB 4096
#define EPS_C 0.2f
#define INV_TEMP 5.0f
#define NCHUNK 4            // j-chunks in infonce (1024 cols each)

#define NRANGE 293          // 256-node ranges
#define RB_U 196            // user-half ranges (0..195; range 195 shared w/ items)
#define RB_I 98             // item-half ranges (195..292 -> rel 0..97)
#define GOFF_I 195
#define EPB 4096            // edges per partition block (both halves)
#define YS 64.0f            // fp8 y scale (keeps elements in e4m3 normal range)
#define YSI (1.0f / 64.0f)

typedef float floatx4 __attribute__((ext_vector_type(4)));
typedef float floatx2 __attribute__((ext_vector_type(2)));
typedef short shortx8 __attribute__((ext_vector_type(8)));

__device__ __forceinline__ float wave_sum(float x) {
#pragma unroll
  for (int m = 32; m >= 1; m >>= 1) x += __shfl_xor(x, m, 64);
  return x;
}

__device__ __forceinline__ unsigned short f2bf(float f) {   // RNE
  unsigned u = __float_as_uint(f);
  u += 0x7fffu + ((u >> 16) & 1u);
  return (unsigned short)(u >> 16);
}
// HW fp8 (OCP e4m3 on gfx950) encode pair / decode single
__device__ __forceinline__ unsigned enc_pk4(float a, float b, float c, float d) {
  int w = 0;
  w = __builtin_amdgcn_cvt_pk_fp8_f32(a, b, w, false);   // bytes 0,1
  w = __builtin_amdgcn_cvt_pk_fp8_f32(c, d, w, true);    // bytes 2,3
  return (unsigned)w;
}
__device__ __forceinline__ float fp8dec1(unsigned char b) {
  return __builtin_amdgcn_cvt_f32_fp8((int)b, 0);
}

// ---------------- zero: counts = 0 ----------------
__global__ __launch_bounds__(256) void zero_kernel(int* __restrict__ counts) {
  int n = blockIdx.x * 256 + threadIdx.x;
  if (n < NNODE) counts[n] = 0;
}

// ---------------- pcount: range histograms -> bcnt column; + per-node degrees --------
__global__ __launch_bounds__(256) void pcount_kernel(const int* __restrict__ src,
                                                     int* __restrict__ bcnt,
                                                     int* __restrict__ counts,
                                                     int ne, int nbu, int nbp) {
  __shared__ int qc[RB_U];
  int t = threadIdx.x;
  int b = blockIdx.x;
  int eh = ne >> 1;
  bool isU = b < nbu;
  int base = isU ? b * EPB : eh + (b - nbu) * EPB;
  int lim = min(base + EPB, isU ? eh : ne);
  int RB = isU ? RB_U : RB_I;
  int goff = isU ? 0 : GOFF_I;
  for (int i = t; i < RB; i += 256) qc[i] = 0;
  __syncthreads();
  for (int i = base + t; i < lim; i += 256) {
    int s = __builtin_nontemporal_load(src + i);
    atomicAdd(&qc[(s >> 8) - goff], 1);
    atomicAdd(&counts[s], 1);          // per-node degree (non-returning, low contention)
  }
  __syncthreads();
  for (int r = t; r < NRANGE; r += 256) {
    int rel = r - goff;
    int v = (rel >= 0 && rel < RB) ? qc[rel] : 0;
    bcnt[(size_t)r * nbp + b] = v;
  }
}

// ---------------- pscan: per range, local exclusive scan over block columns ----------
__global__ __launch_bounds__(256) void pscan_kernel(const int* __restrict__ bcnt,
                                                    int* __restrict__ boff,
                                                    int* __restrict__ rtot, int nbp) {
  __shared__ int s0[512], s1[512];
  int r = blockIdx.x, t = threadIdx.x;
  for (int j = t; j < 512; j += 256) s0[j] = (j < nbp) ? bcnt[(size_t)r * nbp + j] : 0;
  __syncthreads();
  int* a = s0;
  int* bf = s1;
  for (int off = 1; off < 512; off <<= 1) {
    for (int j = t; j < 512; j += 256) bf[j] = a[j] + ((j >= off) ? a[j - off] : 0);
    __syncthreads();
    int* tmp = a; a = bf; bf = tmp;
  }
  for (int j = t; j < nbp; j += 256)
    boff[(size_t)r * nbp + j] = a[j] - bcnt[(size_t)r * nbp + j];
  if (t == 0) rtot[r] = a[511];
}

// ---- inline exclusive scan of rtot[NRANGE] -> cb[] (LDS), 256 threads ---------------
__device__ __forceinline__ void scan_rtot(const int* __restrict__ rtot,
                                          int* s0, int* s1, int* cb, int t) {
  for (int j = t; j < 512; j += 256) s0[j] = (j < NRANGE) ? rtot[j] : 0;
  __syncthreads();
  int* a = s0;
  int* bf = s1;
  for (int off = 1; off < 512; off <<= 1) {
    for (int j = t; j < 512; j += 256) bf[j] = a[j] + ((j >= off) ? a[j - off] : 0);
    __syncthreads();
    int* tmp = a; a = bf; bf = tmp;
  }
  for (int j = t; j < NRANGE; j += 256) cb[j] = a[j] - rtot[j];
  __syncthreads();
}

// ---------------- pscatter: deterministic binning into u32 (srcLow8 | dst) -----------
// cbase computed inline from rtot (no cscan2 kernel).
__global__ __launch_bounds__(256) void pscatter_kernel(const int* __restrict__ src,
                                                       const int* __restrict__ dst,
                                                       const int* __restrict__ boff,
                                                       const int* __restrict__ rtot,
                                                       unsigned* __restrict__ binned,
                                                       int ne, int nbu, int nbp) {
  __shared__ int qc[RB_U];
  __shared__ int s0[512], s1[512], cb[NRANGE];
  int t = threadIdx.x;
  int b = blockIdx.x;
  for (int i = t; i < RB_U; i += 256) qc[i] = 0;
  scan_rtot(rtot, s0, s1, cb, t);     // also covers the qc-zero sync
  int eh = ne >> 1;
  bool isU = b < nbu;
  int base = isU ? b * EPB : eh + (b - nbu) * EPB;
  int lim = min(base + EPB, isU ? eh : ne);
  int goff = isU ? 0 : GOFF_I;
  for (int i = base + t; i < lim; i += 256) {
    int s = __builtin_nontemporal_load(src + i);
    int d = __builtin_nontemporal_load(dst + i);
    int rb = (s >> 8) - goff;
    int pos = atomicAdd(&qc[rb], 1);
    int rg = rb + goff;
    int g = cb[rg] + boff[(size_t)rg * nbp + b] + pos;
    binned[g] = ((unsigned)(s & 255) << 24) | (unsigned)d;   // dst < 2^24
  }
}

// ---------------- place: one block per range -> row_ptr, csr + prescale --------------
// Degrees precomputed (pcount) -> NO histogram pass: load counts, scan for row_ptr,
// single binned pass for the csr scatter, then fused prescale (y_init encode).
__global__ __launch_bounds__(256) void place_kernel(
    const unsigned* __restrict__ binned, const int* __restrict__ rtot,
    const int* __restrict__ counts,
    int* __restrict__ row_ptr, int* __restrict__ csr_dst,
    const float* __restrict__ ut, const float* __restrict__ it,
    unsigned char* __restrict__ y, int ne) {
  __shared__ int cur[256], ws[4], wo[4];
  __shared__ int s0[512], s1[512], cb[NRANGE];
  int t = threadIdx.x;
  int b = blockIdx.x;
  int r0 = b << 8;
  int n = r0 + t;
  scan_rtot(rtot, s0, s1, cb, t);
  int seg0 = cb[b];
  if (b == NRANGE - 1 && t == 0) row_ptr[NNODE] = ne;
  int seg1 = (b == NRANGE - 1) ? ne : cb[b + 1];
  int c = (n < NNODE) ? counts[n] : 0;       // degree (precomputed in pcount)
  int lane = t & 63, wid = t >> 6;
  int v = c;
#pragma unroll
  for (int d = 1; d < 64; d <<= 1) {
    int u = __shfl_up(v, d, 64);
    if (lane >= d) v += u;
  }
  if (lane == 63) ws[wid] = v;
  __syncthreads();
  if (t == 0) {
    int run = 0;
    for (int k = 0; k < 4; ++k) { wo[k] = run; run += ws[k]; }
  }
  __syncthreads();
  int excl = v - c + wo[wid];
  int rp = seg0 + excl;
  if (n < NNODE) row_ptr[n] = rp;
  cur[t] = rp;                                // absolute csr offsets
  __syncthreads();
  for (int j = seg0 + t; j < seg1; j += 256) {
    unsigned e = binned[j];
    int off = atomicAdd(&cur[e >> 24], 1);
    csr_dst[off] = (int)(e & 0xFFFFFFu);
  }
  // ---- fused prescale: y[n] = fp8(table[n] * rsqrt(max(deg,1)) * YS) ----
  if (n <= NNODE) {
    unsigned ow[16];
    if (n == NNODE) {
#pragma unroll
      for (int k = 0; k < 16; ++k) ow[k] = 0u;       // dummy zero row
    } else {
      float sc = rsqrtf(fmaxf((float)c, 1.f)) * YS;
      const float* srcp = (n < UCNT) ? (ut + (size_t)n * DDIM)
                                     : (it + (size_t)(n - UCNT) * DDIM);
#pragma unroll
      for (int k = 0; k < 16; ++k) {
        float4 vv = ((const float4*)srcp)[k];
        ow[k] = enc_pk4(vv.x * sc, vv.y * sc, vv.z * sc, vv.w * sc);
      }
    }
    uint4* yp = (uint4*)(y + (size_t)n * DDIM);
#pragma unroll
    for (int k = 0; k < 4; ++k) yp[k] = *(const uint4*)&ow[k * 4];
  }
}

// ---- gather helpers: 8 edge-groups x 8 dim-slices; issue all, then consume ----------
__device__ __forceinline__ void gather_issue(const unsigned char* __restrict__ yb,
                                             int d, int nit, int g, unsigned voff,
                                             uint2* pk) {
#pragma unroll
  for (int j = 0; j < 8; ++j) {
    if (j < nit) {
      int dj = __shfl(d, j * 8 + g, 64);
      pk[j] = *(const uint2*)(yb + (((unsigned)dj << 6) + voff));   // 32-bit voffset
    }
  }
}
__device__ __forceinline__ void gather_acc(const uint2* pk, int nit,
                                           floatx2& a0, floatx2& a1,
                                           floatx2& a2, floatx2& a3) {
#pragma unroll
  for (int j = 0; j < 8; ++j) {
    if (j < nit) {
      a0 += __builtin_amdgcn_cvt_pk_f32_fp8(pk[j].x, 0);
      a1 += __builtin_amdgcn_cvt_pk_f32_fp8(pk[j].x, 1);
      a2 += __builtin_amdgcn_cvt_pk_f32_fp8(pk[j].y, 0);
      a3 += __builtin_amdgcn_cvt_pk_f32_fp8(pk[j].y, 1);
    }
  }
}

// ---------------- SpMM: 4 adjacent rows per wave, staged select-reduce ---------------
__global__ __launch_bounds__(256) void spmm_kernel(const unsigned char* __restrict__ y_in,
                                                   const int* __restrict__ row_ptr,
                                                   const int* __restrict__ csr_dst,
                                                   const int* __restrict__ counts,
                                                   const float* __restrict__ noise,
                                                   unsigned char* __restrict__ y_out) {
  const int NW = NNODE / 4;   // 18750 full waves
  int wv = __builtin_amdgcn_readfirstlane(blockIdx.x * 4 + (threadIdx.x >> 6));
  int lane = threadIdx.x & 63;
  if (wv > NW) return;
  int g = lane >> 3, l8 = lane & 7;
  unsigned voff = (unsigned)(l8 * 8);
  if (wv == NW) {                     // keep dummy zero row alive in the output buffer
    if (g == 0) {
      uint2 z; z.x = 0u; z.y = 0u;
      *(uint2*)(y_out + (size_t)NNODE * DDIM + voff) = z;
    }
    return;
  }
  int r0 = wv * 4;
  int b0 = row_ptr[r0];               // uniform -> s_load
  int b1 = row_ptr[r0 + 1];
  int b2 = row_ptr[r0 + 2];
  int b3 = row_ptr[r0 + 3];
  int b4 = row_ptr[r0 + 4];
  // prefetch noise rows (consumed in epilogue, hidden under gathers)
  floatx4 nv[4][2];
#pragma unroll
  for (int r = 0; r < 4; ++r) {
    nv[r][0] = __builtin_nontemporal_load((const floatx4*)(noise + (size_t)(r0 + r) * DDIM + l8 * 8));
    nv[r][1] = __builtin_nontemporal_load((const floatx4*)(noise + (size_t)(r0 + r) * DDIM + l8 * 8 + 4));
  }
  float scr0 = rsqrtf(fmaxf((float)counts[r0], 1.f));
  float scr1 = rsqrtf(fmaxf((float)counts[r0 + 1], 1.f));
  float scr2 = rsqrtf(fmaxf((float)counts[r0 + 2], 1.f));
  float scr3 = rsqrtf(fmaxf((float)counts[r0 + 3], 1.f));

  int c0 = min(b1 - b0, 64), c1 = min(b2 - b1, 64);
  int c2 = min(b3 - b2, 64), c3 = min(b4 - b3, 64);
  int nit0 = (c0 + 7) >> 3, nit1 = (c1 + 7) >> 3;
  int nit2 = (c2 + 7) >> 3, nit3 = (c3 + 7) >> 3;
  int d0 = __builtin_nontemporal_load(csr_dst + b0 + lane);   // csr padded by 64 ints
  int d1 = __builtin_nontemporal_load(csr_dst + b1 + lane);
  int d2 = __builtin_nontemporal_load(csr_dst + b2 + lane);
  int d3 = __builtin_nontemporal_load(csr_dst + b3 + lane);
  d0 = (lane < c0) ? d0 : NNODE;      // lanes past cnt -> dummy zero row
  d1 = (lane < c1) ? d1 : NNODE;
  d2 = (lane < c2) ? d2 : NNODE;
  d3 = (lane < c3) ? d3 : NNODE;

  floatx2 a0[4] = {{0.f,0.f},{0.f,0.f},{0.f,0.f},{0.f,0.f}};
  floatx2 a1[4] = {{0.f,0.f},{0.f,0.f},{0.f,0.f},{0.f,0.f}};
  floatx2 a2[4] = {{0.f,0.f},{0.f,0.f},{0.f,0.f},{0.f,0.f}};
  floatx2 a3[4] = {{0.f,0.f},{0.f,0.f},{0.f,0.f},{0.f,0.f}};
  {
    uint2 p0[8], p1[8], p2[8], p3[8];
    gather_issue(y_in, d0, nit0, g, voff, p0);   // all 4 rows' loads in flight
    gather_issue(y_in, d1, nit1, g, voff, p1);
    gather_issue(y_in, d2, nit2, g, voff, p2);
    gather_issue(y_in, d3, nit3, g, voff, p3);
    gather_acc(p0, nit0, a0[0], a0[1], a0[2], a0[3]);
    gather_acc(p1, nit1, a1[0], a1[1], a1[2], a1[3]);
    gather_acc(p2, nit2, a2[0], a2[1], a2[2], a2[3]);
    gather_acc(p3, nit3, a3[0], a3[1], a3[2], a3[3]);
  }
  // rare deg>64 tails, one loop per row
  for (int e0 = b0 + 64; e0 < b1; e0 += 64) {
    int cc = min(b1 - e0, 64); int nn = (cc + 7) >> 3;
    int dd = __builtin_nontemporal_load(csr_dst + e0 + lane);
    dd = (lane < cc) ? dd : NNODE;
    uint2 pp[8];
    gather_issue(y_in, dd, nn, g, voff, pp);
    gather_acc(pp, nn, a0[0], a0[1], a0[2], a0[3]);
  }
  for (int e0 = b1 + 64; e0 < b2; e0 += 64) {
    int cc = min(b2 - e0, 64); int nn = (cc + 7) >> 3;
    int dd = __builtin_nontemporal_load(csr_dst + e0 + lane);
    dd = (lane < cc) ? dd : NNODE;
    uint2 pp[8];
    gather_issue(y_in, dd, nn, g, voff, pp);
    gather_acc(pp, nn, a1[0], a1[1], a1[2], a1[3]);
  }
  for (int e0 = b2 + 64; e0 < b3; e0 += 64) {
    int cc = min(b3 - e0, 64); int nn = (cc + 7) >> 3;
    int dd = __builtin_nontemporal_load(csr_dst + e0 + lane);
    dd = (lane < cc) ? dd : NNODE;
    uint2 pp[8];
    gather_issue(y_in, dd, nn, g, voff, pp);
    gather_acc(pp, nn, a2[0], a2[1], a2[2], a2[3]);
  }
  for (int e0 = b3 + 64; e0 < b4; e0 += 64) {
    int cc = min(b4 - e0, 64); int nn = (cc + 7) >> 3;
    int dd = __builtin_nontemporal_load(csr_dst + e0 + lane);
    dd = (lane < cc) ? dd : NNODE;
    uint2 pp[8];
    gather_issue(y_in, dd, nn, g, voff, pp);
    gather_acc(pp, nn, a3[0], a3[1], a3[2], a3[3]);
  }

  float A0[8] = {a0[0][0], a0[0][1], a0[1][0], a0[1][1], a0[2][0], a0[2][1], a0[3][0], a0[3][1]};
  float A1[8] = {a1[0][0], a1[0][1], a1[1][0], a1[1][1], a1[2][0], a1[2][1], a1[3][0], a1[3][1]};
  float A2[8] = {a2[0][0], a2[0][1], a2[1][0], a2[1][1], a2[2][0], a2[2][1], a2[3][0], a2[3][1]};
  float A3[8] = {a3[0][0], a3[0][1], a3[1][0], a3[1][1], a3[2][0], a3[2][1], a3[3][0], a3[3][1]};

  int gr = g & 3;
  bool hi2 = (gr & 2) != 0, hi1 = (gr & 1) != 0;

  // round 1: xor 32 — plain add, all 4 rows (values now depend on g&3 only)
#pragma unroll
  for (int k = 0; k < 8; ++k) {
    A0[k] += __shfl_xor(A0[k], 32, 64);
    A1[k] += __shfl_xor(A1[k], 32, 64);
    A2[k] += __shfl_xor(A2[k], 32, 64);
    A3[k] += __shfl_xor(A3[k], 32, 64);
  }
  // round 2: xor 16 — exchange ALL rows, keep own[r]+partner[r] for rows with
  // bit1(r) == bit1(class). Classes {0,1} keep rows {0,1}; {2,3} keep rows {2,3}.
  float B0[8], B1[8];
#pragma unroll
  for (int k = 0; k < 8; ++k) {
    float r0v = __shfl_xor(A0[k], 16, 64);
    float r1v = __shfl_xor(A1[k], 16, 64);
    float r2v = __shfl_xor(A2[k], 16, 64);
    float r3v = __shfl_xor(A3[k], 16, 64);
    B0[k] = hi2 ? (A2[k] + r2v) : (A0[k] + r0v);
    B1[k] = hi2 ? (A3[k] + r3v) : (A1[k] + r1v);
  }
  // round 3: xor 8 — exchange both rows, keep the one matching bit0(class)
  float C[8];
#pragma unroll
  for (int k = 0; k < 8; ++k) {
    float s0 = __shfl_xor(B0[k], 8, 64);
    float s1 = __shfl_xor(B1[k], 8, 64);
    C[k] = hi1 ? (B1[k] + s1) : (B0[k] + s0);
  }

  // select this group's noise slices + scale (row r0+gr)
  float sn[8];
#pragma unroll
  for (int k = 0; k < 4; ++k) {
    float lo = hi1 ? nv[1][0][k] : nv[0][0][k];
    float hi = hi1 ? nv[3][0][k] : nv[2][0][k];
    sn[k] = hi2 ? hi : lo;
    float lo2 = hi1 ? nv[1][1][k] : nv[0][1][k];
    float hi2v = hi1 ? nv[3][1][k] : nv[2][1][k];
    sn[4 + k] = hi2 ? hi2v : lo2;
  }
  float scr = hi2 ? (hi1 ? scr3 : scr2) : (hi1 ? scr1 : scr0);

  float ss = 0.f;
#pragma unroll
  for (int k = 0; k < 8; ++k) ss += sn[k] * sn[k];
#pragma unroll
  for (int m = 1; m <= 4; m <<= 1) ss += __shfl_xor(ss, m, 64);  // within 8-lane group
  float inv = EPS_C / fmaxf(sqrtf(ss), 1e-12f);

  float ov[8];
#pragma unroll
  for (int k = 0; k < 8; ++k) {
    float x = C[k] * scr * YSI;
    float sgn = (x > 0.f) ? 1.f : ((x < 0.f) ? -1.f : 0.f);
    ov[k] = (x + sgn * sn[k] * inv) * scr * YS;
  }
  if (g < 4) {                          // groups 0..3 store rows r0..r0+3
    uint2 o;
    o.x = enc_pk4(ov[0], ov[1], ov[2], ov[3]);
    o.y = enc_pk4(ov[4], ov[5], ov[6], ov[7]);
    *(uint2*)(y_out + (((unsigned)(r0 + gr)) << 6) + voff) = o;
  }
}

// ---------------- batch gather: BPR, reg, bf16 normalized InfoNCE inputs -------------
__global__ __launch_bounds__(256) void batch_kernel(
    const unsigned char* __restrict__ yb0, const unsigned char* __restrict__ yb1,
    const unsigned char* __restrict__ yb2,
    const float* __restrict__ ut, const float* __restrict__ it,
    const int* __restrict__ counts,
    const int* __restrict__ user, const int* __restrict__ pos, const int* __restrict__ neg,
    unsigned short* __restrict__ z1u, unsigned short* __restrict__ z2u,
    unsigned short* __restrict__ z1i, unsigned short* __restrict__ z2i,
    float* __restrict__ pos_u, float* __restrict__ pos_i,
    float* __restrict__ sp_arr, float* __restrict__ rr_arr) {
  int wave = blockIdx.x * (blockDim.x >> 6) + (threadIdx.x >> 6);
  int lane = threadIdx.x & 63;
  if (wave >= BB) return;
  int b = wave;
  int iu = user[b], ip = pos[b], ing = neg[b];
  float s_u = sqrtf(fmaxf((float)counts[iu], 1.f)) * YSI;
  float s_p = sqrtf(fmaxf((float)counts[UCNT + ip], 1.f)) * YSI;
  float s_n = sqrtf(fmaxf((float)counts[UCNT + ing], 1.f)) * YSI;
  size_t ru = (size_t)iu * DDIM + lane;
  size_t rp = (size_t)(UCNT + ip) * DDIM + lane;
  size_t rn = (size_t)(UCNT + ing) * DDIM + lane;
  float cu = fp8dec1(yb0[ru]) * s_u;        // x_cl user row
  float ci = fp8dec1(yb0[rp]) * s_p;        // x_cl positive-item row
  float ue = (cu + (fp8dec1(yb1[ru]) + fp8dec1(yb2[ru])) * s_u) * (1.f / 3.f);
  float pe = (ci + (fp8dec1(yb1[rp]) + fp8dec1(yb2[rp])) * s_p) * (1.f / 3.f);
  float ne = (fp8dec1(yb0[rn]) + fp8dec1(yb1[rn]) + fp8dec1(yb2[rn])) * s_n * (1.f / 3.f);

  float ps = wave_sum(ue * pe);
  float ns = wave_sum(ue * ne);
  float x = ns - ps;
  float sp = fmaxf(x, 0.f) + log1pf(expf(-fabsf(x)));

  float eu = ut[(size_t)iu * DDIM + lane];
  float ep = it[(size_t)ip * DDIM + lane];
  float en = it[(size_t)ing * DDIM + lane];
  float rr = wave_sum(eu * eu + ep * ep + en * en);
  if (lane == 0) { sp_arr[b] = sp; rr_arr[b] = rr; }

  float n1 = fmaxf(sqrtf(wave_sum(cu * cu)), 1e-12f);
  float n2 = fmaxf(sqrtf(wave_sum(ue * ue)), 1e-12f);
  float d12 = wave_sum(cu * ue);
  z1u[(size_t)b * DDIM + lane] = f2bf(cu / n1);
  z2u[(size_t)b * DDIM + lane] = f2bf(ue / n2);
  if (lane == 0) pos_u[b] = d12 / (n1 * n2) * INV_TEMP;

  float m1 = fmaxf(sqrtf(wave_sum(ci * ci)), 1e-12f);
  float m2 = fmaxf(sqrtf(wave_sum(pe * pe)), 1e-12f);
  float e12 = wave_sum(ci * pe);
  z1i[(size_t)b * DDIM + lane] = f2bf(ci / m1);
  z2i[(size_t)b * DDIM + lane] = f2bf(pe / m2);
  if (lane == 0) pos_i[b] = e12 / (m1 * m2) * INV_TEMP;
}

// ---------------- InfoNCE via MFMA: wave = 16 rows x 1024-col chunk ------------------
__global__ __launch_bounds__(256) void infonce_kernel(const unsigned short* __restrict__ Z1u,
                                                      const unsigned short* __restrict__ Z2u,
                                                      const unsigned short* __restrict__ Z1i,
                                                      const unsigned short* __restrict__ Z2i,
                                                      float* __restrict__ rowpart_u,
                                                      float* __restrict__ rowpart_i) {
  const unsigned short* Z1 = blockIdx.z ? Z1i : Z1u;
  const unsigned short* Z2 = blockIdx.z ? Z2i : Z2u;
  float* rowpart = blockIdx.z ? rowpart_i : rowpart_u;
  int t = threadIdx.x;
  int wv = t >> 6, lane = t & 63;
  int i0 = (blockIdx.y * 4 + wv) * 16;   // wave's 16-row group (0..255 groups)
  int j0 = blockIdx.x * (BB / NCHUNK);   // chunk base (1024 cols)
  int m = lane & 15, q = lane >> 4;
  const unsigned short* ap = Z1 + (size_t)(i0 + m) * DDIM + q * 8;
  shortx8 a0 = *(const shortx8*)ap;
  shortx8 a1 = *(const shortx8*)(ap + 32);
  const unsigned short* bp = Z2 + (size_t)(j0 + m) * DDIM + q * 8;
  float rs[4] = {0.f, 0.f, 0.f, 0.f};
#pragma unroll 4
  for (int jt = 0; jt < (BB / NCHUNK) / 16; ++jt) {   // 64 j-tiles
    shortx8 b0 = *(const shortx8*)(bp + (size_t)jt * 16 * DDIM);
    shortx8 b1 = *(const shortx8*)(bp + (size_t)jt * 16 * DDIM + 32);
    floatx4 acc = {0.f, 0.f, 0.f, 0.f};
    acc = __builtin_amdgcn_mfma_f32_16x16x32_bf16(a0, b0, acc, 0, 0, 0);
    acc = __builtin_amdgcn_mfma_f32_16x16x32_bf16(a1, b1, acc, 0, 0, 0);
#pragma unroll
    for (int r = 0; r < 4; ++r) rs[r] += __expf(acc[r] * INV_TEMP);
  }
#pragma unroll
  for (int mm = 1; mm <= 8; mm <<= 1)
#pragma unroll
    for (int r = 0; r < 4; ++r) rs[r] += __shfl_xor(rs[r], mm, 64);
  if (m == 0) {
#pragma unroll
    for (int r = 0; r < 4; ++r)
      rowpart[(size_t)blockIdx.x * BB + i0 + q * 4 + r] = rs[r];
  }
}

// ---------------- finalize (inlines the NCHUNK rowpart reduction) ----------------
__global__ __launch_bounds__(256) void finalize_kernel(const float* __restrict__ rowpart_u,
                                                       const float* __restrict__ pos_u,
                                                       const float* __restrict__ rowpart_i,
                                                       const float* __restrict__ pos_i,
                                                       const float* __restrict__ sp_arr,
                                                       const float* __restrict__ rr_arr,
                                                       float* __restrict__ out) {
  int t = threadIdx.x;
  float su = 0.f, si = 0.f, sb = 0.f, sr = 0.f;
  for (int i = t; i < BB; i += 256) {
    float ru = 0.f, ri = 0.f;
#pragma unroll
    for (int jb = 0; jb < NCHUNK; ++jb) {
      ru += rowpart_u[(size_t)jb * BB + i];
      ri += rowpart_i[(size_t)jb * BB + i];
    }
    su += logf(ru) - pos_u[i];
    si += logf(ri) - pos_i[i];
    sb += sp_arr[i];
    sr += rr_arr[i];
  }
  su = wave_sum(su);
  si = wave_sum(si);
  sb = wave_sum(sb);
  sr = wave_sum(sr);
  __shared__ float sh[16];
  int lane = t & 63, wid = t >> 6;
  if (lane == 0) { sh[wid] = su; sh[4 + wid] = si; sh[8 + wid] = sb; sh[12 + wid] = sr; }
  __syncthreads();
  if (t == 0) {
    float SU = sh[0] + sh[1] + sh[2] + sh[3];
    float SI = sh[4] + sh[5] + sh[6] + sh[7];
    float SB = sh[8] + sh[9] + sh[10] + sh[11];
    float SR = sh[12] + sh[13] + sh[14] + sh[15];
    out[0] = SB * (1.f / BB);
    out[1] = 1e-4f * 0.5f * SR * (1.f / BB);
    out[2] = 0.2f * ((SU + SI) * (1.f / BB));
  }
}

extern "C" void kernel_launch(void* const* d_in, const int* in_sizes, int n_in,
                              void* d_out, int out_size, void* d_ws, size_t ws_size,
                              hipStream_t stream) {
  const float* user_table = (const float*)d_in[0];
  const float* item_table = (const float*)d_in[1];
  const float* noise      = (const float*)d_in[3];
  const int*   edge_src   = (const int*)d_in[4];
  const int*   edge_dst   = (const int*)d_in[5];
  const int*   user       = (const int*)d_in[6];
  const int*   positive   = (const int*)d_in[7];
  const int*   negative   = (const int*)d_in[8];
  const int E2 = in_sizes[2];  // 2,000,000

  const int eh = E2 >> 1;
  const int nbu = (eh + EPB - 1) / EPB;            // 245
  const int nbi = (E2 - eh + EPB - 1) / EPB;       // 245
  const int nbp = nbu + nbi;                       // 490

  char* w = (char*)d_ws;
  auto alloc = [&](size_t bytes) -> void* {
    void* p = (void*)w;
    w += (bytes + 255) & ~(size_t)255;
    return p;
  };
  int*   rtot     = (int*)alloc((size_t)NRANGE * 4);
  int*   bcnt     = (int*)alloc((size_t)NRANGE * nbp * 4);
  int*   boff     = (int*)alloc((size_t)NRANGE * nbp * 4);
  int*   row_ptr  = (int*)alloc((size_t)(NNODE + 1) * 4);
  int*   counts   = (int*)alloc((size_t)NNODE * 4);
  int*   csr_dst  = (int*)alloc((size_t)(E2 + 64) * 4);   // +64 pad: unpredicated chunk load
  unsigned* binned = (unsigned*)alloc((size_t)E2 * 4);
  unsigned char* y_init = (unsigned char*)alloc((size_t)(NNODE + 1) * DDIM);
  unsigned char* yb0    = (unsigned char*)alloc((size_t)(NNODE + 1) * DDIM);
  unsigned char* yb1    = (unsigned char*)alloc((size_t)(NNODE + 1) * DDIM);
  unsigned char* yb2    = (unsigned char*)alloc((size_t)(NNODE + 1) * DDIM);
  unsigned short* z1u    = (unsigned short*)alloc((size_t)BB * DDIM * 2);
  unsigned short* z2u    = (unsigned short*)alloc((size_t)BB * DDIM * 2);
  unsigned short* z1i    = (unsigned short*)alloc((size_t)BB * DDIM * 2);
  unsigned short* z2i    = (unsigned short*)alloc((size_t)BB * DDIM * 2);
  float* pos_u    = (float*)alloc((size_t)BB * 4);
  float* pos_i    = (float*)alloc((size_t)BB * 4);
  float* sp_arr   = (float*)alloc((size_t)BB * 4);
  float* rr_arr   = (float*)alloc((size_t)BB * 4);
  float* rowpart_u = (float*)alloc((size_t)NCHUNK * BB * 4);
  float* rowpart_i = (float*)alloc((size_t)NCHUNK * BB * 4);

  zero_kernel<<<(NNODE + 255) / 256, 256, 0, stream>>>(counts);
  pcount_kernel<<<nbp, 256, 0, stream>>>(edge_src, bcnt, counts, E2, nbu, nbp);
  pscan_kernel<<<NRANGE, 256, 0, stream>>>(bcnt, boff, rtot, nbp);
  pscatter_kernel<<<nbp, 256, 0, stream>>>(edge_src, edge_dst, boff, rtot, binned,
                                           E2, nbu, nbp);
  place_kernel<<<NRANGE, 256, 0, stream>>>(binned, rtot, counts, row_ptr, csr_dst,
                                           user_table, item_table, y_init, E2);
  const int spmm_waves = NNODE / 4 + 1;         // 4 rows per wave + dummy-row wave
  const int spmm_blocks = (spmm_waves + 3) / 4; // 4 waves per 256-thread block
  spmm_kernel<<<spmm_blocks, 256, 0, stream>>>(y_init, row_ptr, csr_dst, counts,
                                               noise + (size_t)0 * NNODE * DDIM, yb0);
  spmm_kernel<<<spmm_blocks, 256, 0, stream>>>(yb0, row_ptr, csr_dst, counts,
                                               noise + (size_t)1 * NNODE * DDIM, yb1);
  spmm_kernel<<<spmm_blocks, 256, 0, stream>>>(yb1, row_ptr, csr_dst, counts,
                                               noise + (size_t)2 * NNODE * DDIM, yb2);
  batch_kernel<<<BB / 4, 256, 0, stream>>>(yb0, yb1, yb2, user_table, item_table, counts,
                                           user, positive, negative,
                                           z1u, z2u, z1i, z2i, pos_u, pos_i, sp_arr, rr_arr);
  dim3 ig(NCHUNK, BB / 64, 2);   // 4 chunks x 64 blocks.y (4 i-groups each) x {u,i}
  infonce_kernel<<<ig, 256, 0, stream>>>(z1u, z2u, z1i, z2i, rowpart_u, rowpart_i);
  finalize_kernel<<<1, 256, 0, stream>>>(rowpart_u, pos_u, rowpart_i, pos_i,
                                         sp_arr, rr_arr, (float*)d_out);
}

// Round 12
// 330.145 us; speedup vs baseline: 1.2461x; 1.2461x over previous
//
#include <hip/hip_runtime.h>
#include <hip/hip_bf16.h>
#include <hip/hip_fp8.h>
#include <math.h>

#define UCNT 50000
#define ICNT 25000
#define NNODE 75000
#define DDIM 64
#define BB 4096
#define EPS_C 0.2f
#define INV_TEMP 5.0f
#define NCHUNK 4            // j-chunks in infonce (1024 cols each)

#define NRANGE 293          // 256-node ranges
#define RB_U 196            // user-half ranges (0..195; range 195 shared w/ items)
#define RB_I 98             // item-half ranges (195..292 -> rel 0..97)
#define GOFF_I 195
#define EPB 4096            // edges per partition block (both halves)
#define YS 64.0f            // fp8 y scale (keeps elements in e4m3 normal range)
#define YSI (1.0f / 64.0f)

typedef float floatx4 __attribute__((ext_vector_type(4)));
typedef float floatx2 __attribute__((ext_vector_type(2)));
typedef short shortx8 __attribute__((ext_vector_type(8)));

__device__ __forceinline__ float wave_sum(float x) {
#pragma unroll
  for (int m = 32; m >= 1; m >>= 1) x += __shfl_xor(x, m, 64);
  return x;
}

__device__ __forceinline__ unsigned short f2bf(float f) {   // RNE
  unsigned u = __float_as_uint(f);
  u += 0x7fffu + ((u >> 16) & 1u);
  return (unsigned short)(u >> 16);
}
// HW fp8 (OCP e4m3 on gfx950) encode pair / decode single
__device__ __forceinline__ unsigned enc_pk4(float a, float b, float c, float d) {
  int w = 0;
  w = __builtin_amdgcn_cvt_pk_fp8_f32(a, b, w, false);   // bytes 0,1
  w = __builtin_amdgcn_cvt_pk_fp8_f32(c, d, w, true);    // bytes 2,3
  return (unsigned)w;
}
__device__ __forceinline__ float fp8dec1(unsigned char b) {
  return __builtin_amdgcn_cvt_f32_fp8((int)b, 0);
}

// ---------------- pcount: per (stripe-block, range) histogram -> bcnt column ---------
__global__ __launch_bounds__(256) void pcount_kernel(const int* __restrict__ src,
                                                     int* __restrict__ bcnt,
                                                     int ne, int nbu, int nbp) {
  __shared__ int qc[RB_U];
  int t = threadIdx.x;
  int b = blockIdx.x;
  int eh = ne >> 1;
  bool isU = b < nbu;
  int base = isU ? b * EPB : eh + (b - nbu) * EPB;
  int lim = min(base + EPB, isU ? eh : ne);
  int RB = isU ? RB_U : RB_I;
  int goff = isU ? 0 : GOFF_I;
  for (int i = t; i < RB; i += 256) qc[i] = 0;
  __syncthreads();
  for (int i = base + t; i < lim; i += 256) {
    int s = __builtin_nontemporal_load(src + i);
    atomicAdd(&qc[(s >> 8) - goff], 1);
  }
  __syncthreads();
  for (int r = t; r < NRANGE; r += 256) {
    int rel = r - goff;
    int v = (rel >= 0 && rel < RB) ? qc[rel] : 0;
    bcnt[(size_t)r * nbp + b] = v;
  }
}

// ---------------- pscan: per range, local exclusive scan over block columns ----------
__global__ __launch_bounds__(256) void pscan_kernel(const int* __restrict__ bcnt,
                                                    int* __restrict__ boff,
                                                    int* __restrict__ rtot, int nbp) {
  __shared__ int s0[512], s1[512];
  int r = blockIdx.x, t = threadIdx.x;
  for (int j = t; j < 512; j += 256) s0[j] = (j < nbp) ? bcnt[(size_t)r * nbp + j] : 0;
  __syncthreads();
  int* a = s0;
  int* bf = s1;
  for (int off = 1; off < 512; off <<= 1) {
    for (int j = t; j < 512; j += 256) bf[j] = a[j] + ((j >= off) ? a[j - off] : 0);
    __syncthreads();
    int* tmp = a; a = bf; bf = tmp;
  }
  for (int j = t; j < nbp; j += 256)
    boff[(size_t)r * nbp + j] = a[j] - bcnt[(size_t)r * nbp + j];
  if (t == 0) rtot[r] = a[511];
}

// ---- inline exclusive scan of rtot[NRANGE] -> cb[] (LDS), nthr threads --------------
__device__ __forceinline__ void scan_rtot(const int* __restrict__ rtot,
                                          int* s0, int* s1, int* cb, int t, int nthr) {
  for (int j = t; j < 512; j += nthr) s0[j] = (j < NRANGE) ? rtot[j] : 0;
  __syncthreads();
  int* a = s0;
  int* bf = s1;
  for (int off = 1; off < 512; off <<= 1) {
    for (int j = t; j < 512; j += nthr) bf[j] = a[j] + ((j >= off) ? a[j - off] : 0);
    __syncthreads();
    int* tmp = a; a = bf; bf = tmp;
  }
  for (int j = t; j < NRANGE; j += nthr) cb[j] = a[j] - rtot[j];
  __syncthreads();
}

// ---------------- pscatter: deterministic binning into u32 (srcLow8 | dst) -----------
// 512 threads: halves the serial stripe-loop trip count; cbase inline from rtot.
__global__ __launch_bounds__(512) void pscatter_kernel(const int* __restrict__ src,
                                                       const int* __restrict__ dst,
                                                       const int* __restrict__ boff,
                                                       const int* __restrict__ rtot,
                                                       unsigned* __restrict__ binned,
                                                       int ne, int nbu, int nbp) {
  __shared__ int qc[RB_U];
  __shared__ int s0[512], s1[512], cb[NRANGE];
  int t = threadIdx.x;
  int b = blockIdx.x;
  for (int i = t; i < RB_U; i += 512) qc[i] = 0;
  scan_rtot(rtot, s0, s1, cb, t, 512);  // also covers the qc-zero sync
  int eh = ne >> 1;
  bool isU = b < nbu;
  int base = isU ? b * EPB : eh + (b - nbu) * EPB;
  int lim = min(base + EPB, isU ? eh : ne);
  int goff = isU ? 0 : GOFF_I;
  for (int i = base + t; i < lim; i += 512) {
    int s = __builtin_nontemporal_load(src + i);
    int d = __builtin_nontemporal_load(dst + i);
    int rb = (s >> 8) - goff;
    int pos = atomicAdd(&qc[rb], 1);
    int rg = rb + goff;
    int g = cb[rg] + boff[(size_t)rg * nbp + b] + pos;
    binned[g] = ((unsigned)(s & 255) << 24) | (unsigned)d;   // dst < 2^24
  }
}

// ---------------- place: one block per range -> row_ptr, counts, csr + prescale ------
// 512 threads: histogram + scatter passes halve their trip counts. Node-scan section
// guarded to t<256. Fused prescale (y_init encode) at the end.
__global__ __launch_bounds__(512) void place_kernel(
    const unsigned* __restrict__ binned, const int* __restrict__ rtot,
    int* __restrict__ row_ptr, int* __restrict__ counts,
    int* __restrict__ csr_dst,
    const float* __restrict__ ut, const float* __restrict__ it,
    unsigned char* __restrict__ y, int ne) {
  __shared__ int cnt[256], cur[256], ws[4], wo[4];
  __shared__ int s0[512], s1[512], cb[NRANGE];
  int t = threadIdx.x;
  int b = blockIdx.x;
  int r0 = b << 8;
  int n = r0 + t;
  if (t < 256) cnt[t] = 0;
  scan_rtot(rtot, s0, s1, cb, t, 512);  // also covers the cnt-zero sync
  int seg0 = cb[b];
  int seg1 = (b == NRANGE - 1) ? ne : cb[b + 1];
  if (b == NRANGE - 1 && t == 0) row_ptr[NNODE] = ne;
  for (int j = seg0 + t; j < seg1; j += 512)
    atomicAdd(&cnt[binned[j] >> 24], 1);
  __syncthreads();
  int lane = t & 63, wid = t >> 6;
  int c = (t < 256) ? cnt[t] : 0;
  int v = c;
#pragma unroll
  for (int d = 1; d < 64; d <<= 1) {
    int u = __shfl_up(v, d, 64);
    if (lane >= d) v += u;
  }
  if (lane == 63 && wid < 4) ws[wid] = v;
  __syncthreads();
  if (t == 0) {
    int run = 0;
    for (int k = 0; k < 4; ++k) { wo[k] = run; run += ws[k]; }
  }
  __syncthreads();
  if (t < 256) {
    int excl = v - c + wo[wid];
    if (n < NNODE) {
      row_ptr[n] = seg0 + excl;
      counts[n] = c;
    }
    cur[t] = excl;
  }
  __syncthreads();
  for (int j = seg0 + t; j < seg1; j += 512) {
    unsigned e = binned[j];
    int off = atomicAdd(&cur[e >> 24], 1);
    csr_dst[seg0 + off] = (int)(e & 0xFFFFFFu);
  }
  // ---- fused prescale: y[n] = fp8(table[n] * rsqrt(max(deg,1)) * YS) ----
  if (t < 256 && n <= NNODE) {
    unsigned ow[16];
    if (n == NNODE) {
#pragma unroll
      for (int k = 0; k < 16; ++k) ow[k] = 0u;       // dummy zero row
    } else {
      float sc = rsqrtf(fmaxf((float)c, 1.f)) * YS;
      const float* srcp = (n < UCNT) ? (ut + (size_t)n * DDIM)
                                     : (it + (size_t)(n - UCNT) * DDIM);
#pragma unroll
      for (int k = 0; k < 16; ++k) {
        float4 vv = ((const float4*)srcp)[k];
        ow[k] = enc_pk4(vv.x * sc, vv.y * sc, vv.z * sc, vv.w * sc);
      }
    }
    uint4* yp = (uint4*)(y + (size_t)n * DDIM);
#pragma unroll
    for (int k = 0; k < 4; ++k) yp[k] = *(const uint4*)&ow[k * 4];
  }
}

// ---- gather helpers: 8 edge-groups x 8 dim-slices; issue all, then consume ----------
__device__ __forceinline__ void gather_issue(const unsigned char* __restrict__ yb,
                                             int d, int nit, int g, unsigned voff,
                                             uint2* pk) {
#pragma unroll
  for (int j = 0; j < 8; ++j) {
    if (j < nit) {
      int dj = __shfl(d, j * 8 + g, 64);
      pk[j] = *(const uint2*)(yb + (((unsigned)dj << 6) + voff));   // 32-bit voffset
    }
  }
}
__device__ __forceinline__ void gather_acc(const uint2* pk, int nit,
                                           floatx2& a0, floatx2& a1,
                                           floatx2& a2, floatx2& a3) {
#pragma unroll
  for (int j = 0; j < 8; ++j) {
    if (j < nit) {
      a0 += __builtin_amdgcn_cvt_pk_f32_fp8(pk[j].x, 0);
      a1 += __builtin_amdgcn_cvt_pk_f32_fp8(pk[j].x, 1);
      a2 += __builtin_amdgcn_cvt_pk_f32_fp8(pk[j].y, 0);
      a3 += __builtin_amdgcn_cvt_pk_f32_fp8(pk[j].y, 1);
    }
  }
}

// ---------------- SpMM: 4 adjacent rows per wave, staged select-reduce ---------------
__global__ __launch_bounds__(256) void spmm_kernel(const unsigned char* __restrict__ y_in,
                                                   const int* __restrict__ row_ptr,
                                                   const int* __restrict__ csr_dst,
                                                   const int* __restrict__ counts,
                                                   const float* __restrict__ noise,
                                                   unsigned char* __restrict__ y_out) {
  const int NW = NNODE / 4;   // 18750 full waves
  int wv = __builtin_amdgcn_readfirstlane(blockIdx.x * 4 + (threadIdx.x >> 6));
  int lane = threadIdx.x & 63;
  if (wv > NW) return;
  int g = lane >> 3, l8 = lane & 7;
  unsigned voff = (unsigned)(l8 * 8);
  if (wv == NW) {                     // keep dummy zero row alive in the output buffer
    if (g == 0) {
      uint2 z; z.x = 0u; z.y = 0u;
      *(uint2*)(y_out + (size_t)NNODE * DDIM + voff) = z;
    }
    return;
  }
  int r0 = wv * 4;
  int b0 = row_ptr[r0];               // uniform -> s_load
  int b1 = row_ptr[r0 + 1];
  int b2 = row_ptr[r0 + 2];
  int b3 = row_ptr[r0 + 3];
  int b4 = row_ptr[r0 + 4];
  // prefetch noise rows (consumed in epilogue, hidden under gathers)
  floatx4 nv[4][2];
#pragma unroll
  for (int r = 0; r < 4; ++r) {
    nv[r][0] = __builtin_nontemporal_load((const floatx4*)(noise + (size_t)(r0 + r) * DDIM + l8 * 8));
    nv[r][1] = __builtin_nontemporal_load((const floatx4*)(noise + (size_t)(r0 + r) * DDIM + l8 * 8 + 4));
  }
  float scr0 = rsqrtf(fmaxf((float)counts[r0], 1.f));
  float scr1 = rsqrtf(fmaxf((float)counts[r0 + 1], 1.f));
  float scr2 = rsqrtf(fmaxf((float)counts[r0 + 2], 1.f));
  float scr3 = rsqrtf(fmaxf((float)counts[r0 + 3], 1.f));

  int c0 = min(b1 - b0, 64), c1 = min(b2 - b1, 64);
  int c2 = min(b3 - b2, 64), c3 = min(b4 - b3, 64);
  int nit0 = (c0 + 7) >> 3, nit1 = (c1 + 7) >> 3;
  int nit2 = (c2 + 7) >> 3, nit3 = (c3 + 7) >> 3;
  int d0 = __builtin_nontemporal_load(csr_dst + b0 + lane);   // csr padded by 64 ints
  int d1 = __builtin_nontemporal_load(csr_dst + b1 + lane);
  int d2 = __builtin_nontemporal_load(csr_dst + b2 + lane);
  int d3 = __builtin_nontemporal_load(csr_dst + b3 + lane);
  d0 = (lane < c0) ? d0 : NNODE;      // lanes past cnt -> dummy zero row
  d1 = (lane < c1) ? d1 : NNODE;
  d2 = (lane < c2) ? d2 : NNODE;
  d3 = (lane < c3) ? d3 : NNODE;

  floatx2 a0[4] = {{0.f,0.f},{0.f,0.f},{0.f,0.f},{0.f,0.f}};
  floatx2 a1[4] = {{0.f,0.f},{0.f,0.f},{0.f,0.f},{0.f,0.f}};
  floatx2 a2[4] = {{0.f,0.f},{0.f,0.f},{0.f,0.f},{0.f,0.f}};
  floatx2 a3[4] = {{0.f,0.f},{0.f,0.f},{0.f,0.f},{0.f,0.f}};
  {
    uint2 p0[8], p1[8], p2[8], p3[8];
    gather_issue(y_in, d0, nit0, g, voff, p0);   // all 4 rows' loads in flight
    gather_issue(y_in, d1, nit1, g, voff, p1);
    gather_issue(y_in, d2, nit2, g, voff, p2);
    gather_issue(y_in, d3, nit3, g, voff, p3);
    gather_acc(p0, nit0, a0[0], a0[1], a0[2], a0[3]);
    gather_acc(p1, nit1, a1[0], a1[1], a1[2], a1[3]);
    gather_acc(p2, nit2, a2[0], a2[1], a2[2], a2[3]);
    gather_acc(p3, nit3, a3[0], a3[1], a3[2], a3[3]);
  }
  // rare deg>64 tails, one loop per row
  for (int e0 = b0 + 64; e0 < b1; e0 += 64) {
    int cc = min(b1 - e0, 64); int nn = (cc + 7) >> 3;
    int dd = __builtin_nontemporal_load(csr_dst + e0 + lane);
    dd = (lane < cc) ? dd : NNODE;
    uint2 pp[8];
    gather_issue(y_in, dd, nn, g, voff, pp);
    gather_acc(pp, nn, a0[0], a0[1], a0[2], a0[3]);
  }
  for (int e0 = b1 + 64; e0 < b2; e0 += 64) {
    int cc = min(b2 - e0, 64); int nn = (cc + 7) >> 3;
    int dd = __builtin_nontemporal_load(csr_dst + e0 + lane);
    dd = (lane < cc) ? dd : NNODE;
    uint2 pp[8];
    gather_issue(y_in, dd, nn, g, voff, pp);
    gather_acc(pp, nn, a1[0], a1[1], a1[2], a1[3]);
  }
  for (int e0 = b2 + 64; e0 < b3; e0 += 64) {
    int cc = min(b3 - e0, 64); int nn = (cc + 7) >> 3;
    int dd = __builtin_nontemporal_load(csr_dst + e0 + lane);
    dd = (lane < cc) ? dd : NNODE;
    uint2 pp[8];
    gather_issue(y_in, dd, nn, g, voff, pp);
    gather_acc(pp, nn, a2[0], a2[1], a2[2], a2[3]);
  }
  for (int e0 = b3 + 64; e0 < b4; e0 += 64) {
    int cc = min(b4 - e0, 64); int nn = (cc + 7) >> 3;
    int dd = __builtin_nontemporal_load(csr_dst + e0 + lane);
    dd = (lane < cc) ? dd : NNODE;
    uint2 pp[8];
    gather_issue(y_in, dd, nn, g, voff, pp);
    gather_acc(pp, nn, a3[0], a3[1], a3[2], a3[3]);
  }

  float A0[8] = {a0[0][0], a0[0][1], a0[1][0], a0[1][1], a0[2][0], a0[2][1], a0[3][0], a0[3][1]};
  float A1[8] = {a1[0][0], a1[0][1], a1[1][0], a1[1][1], a1[2][0], a1[2][1], a1[3][0], a1[3][1]};
  float A2[8] = {a2[0][0], a2[0][1], a2[1][0], a2[1][1], a2[2][0], a2[2][1], a2[3][0], a2[3][1]};
  float A3[8] = {a3[0][0], a3[0][1], a3[1][0], a3[1][1], a3[2][0], a3[2][1], a3[3][0], a3[3][1]};

  int gr = g & 3;
  bool hi2 = (gr & 2) != 0, hi1 = (gr & 1) != 0;

  // round 1: xor 32 — plain add, all 4 rows (values now depend on g&3 only)
#pragma unroll
  for (int k = 0; k < 8; ++k) {
    A0[k] += __shfl_xor(A0[k], 32, 64);
    A1[k] += __shfl_xor(A1[k], 32, 64);
    A2[k] += __shfl_xor(A2[k], 32, 64);
    A3[k] += __shfl_xor(A3[k], 32, 64);
  }
  // round 2: xor 16 — exchange ALL rows, keep own[r]+partner[r] for rows with
  // bit1(r) == bit1(class). Classes {0,1} keep rows {0,1}; {2,3} keep rows {2,3}.
  float B0[8], B1[8];
#pragma unroll
  for (int k = 0; k < 8; ++k) {
    float r0v = __shfl_xor(A0[k], 16, 64);
    float r1v = __shfl_xor(A1[k], 16, 64);
    float r2v = __shfl_xor(A2[k], 16, 64);
    float r3v = __shfl_xor(A3[k], 16, 64);
    B0[k] = hi2 ? (A2[k] + r2v) : (A0[k] + r0v);
    B1[k] = hi2 ? (A3[k] + r3v) : (A1[k] + r1v);
  }
  // round 3: xor 8 — exchange both rows, keep the one matching bit0(class)
  float C[8];
#pragma unroll
  for (int k = 0; k < 8; ++k) {
    float s0 = __shfl_xor(B0[k], 8, 64);
    float s1 = __shfl_xor(B1[k], 8, 64);
    C[k] = hi1 ? (B1[k] + s1) : (B0[k] + s0);
  }

  // select this group's noise slices + scale (row r0+gr)
  float sn[8];
#pragma unroll
  for (int k = 0; k < 4; ++k) {
    float lo = hi1 ? nv[1][0][k] : nv[0][0][k];
    float hi = hi1 ? nv[3][0][k] : nv[2][0][k];
    sn[k] = hi2 ? hi : lo;
    float lo2 = hi1 ? nv[1][1][k] : nv[0][1][k];
    float hi2v = hi1 ? nv[3][1][k] : nv[2][1][k];
    sn[4 + k] = hi2 ? hi2v : lo2;
  }
  float scr = hi2 ? (hi1 ? scr3 : scr2) : (hi1 ? scr1 : scr0);

  float ss = 0.f;
#pragma unroll
  for (int k = 0; k < 8; ++k) ss += sn[k] * sn[k];
#pragma unroll
  for (int m = 1; m <= 4; m <<= 1) ss += __shfl_xor(ss, m, 64);  // within 8-lane group
  float inv = EPS_C / fmaxf(sqrtf(ss), 1e-12f);

  float ov[8];
#pragma unroll
  for (int k = 0; k < 8; ++k) {
    float x = C[k] * scr * YSI;
    float sgn = (x > 0.f) ? 1.f : ((x < 0.f) ? -1.f : 0.f);
    ov[k] = (x + sgn * sn[k] * inv) * scr * YS;
  }
  if (g < 4) {                          // groups 0..3 store rows r0..r0+3
    uint2 o;
    o.x = enc_pk4(ov[0], ov[1], ov[2], ov[3]);
    o.y = enc_pk4(ov[4], ov[5], ov[6], ov[7]);
    *(uint2*)(y_out + (((unsigned)(r0 + gr)) << 6) + voff) = o;
  }
}

// ---------------- batch gather: BPR, reg, bf16 normalized InfoNCE inputs -------------
__global__ __launch_bounds__(256) void batch_kernel(
    const unsigned char* __restrict__ yb0, const unsigned char* __restrict__ yb1,
    const unsigned char* __restrict__ yb2,
    const float* __restrict__ ut, const float* __restrict__ it,
    const int* __restrict__ counts,
    const int* __restrict__ user, const int* __restrict__ pos, const int* __restrict__ neg,
    unsigned short* __restrict__ z1u, unsigned short* __restrict__ z2u,
    unsigned short* __restrict__ z1i, unsigned short* __restrict__ z2i,
    float* __restrict__ pos_u, float* __restrict__ pos_i,
    float* __restrict__ sp_arr, float* __restrict__ rr_arr) {
  int wave = blockIdx.x * (blockDim.x >> 6) + (threadIdx.x >> 6);
  int lane = threadIdx.x & 63;
  if (wave >= BB) return;
  int b = wave;
  int iu = user[b], ip = pos[b], ing = neg[b];
  float s_u = sqrtf(fmaxf((float)counts[iu], 1.f)) * YSI;
  float s_p = sqrtf(fmaxf((float)counts[UCNT + ip], 1.f)) * YSI;
  float s_n = sqrtf(fmaxf((float)counts[UCNT + ing], 1.f)) * YSI;
  size_t ru = (size_t)iu * DDIM + lane;
  size_t rp = (size_t)(UCNT + ip) * DDIM + lane;
  size_t rn = (size_t)(UCNT + ing) * DDIM + lane;
  float cu = fp8dec1(yb0[ru]) * s_u;        // x_cl user row
  float ci = fp8dec1(yb0[rp]) * s_p;        // x_cl positive-item row
  float ue = (cu + (fp8dec1(yb1[ru]) + fp8dec1(yb2[ru])) * s_u) * (1.f / 3.f);
  float pe = (ci + (fp8dec1(yb1[rp]) + fp8dec1(yb2[rp])) * s_p) * (1.f / 3.f);
  float ne = (fp8dec1(yb0[rn]) + fp8dec1(yb1[rn]) + fp8dec1(yb2[rn])) * s_n * (1.f / 3.f);

  float ps = wave_sum(ue * pe);
  float ns = wave_sum(ue * ne);
  float x = ns - ps;
  float sp = fmaxf(x, 0.f) + log1pf(expf(-fabsf(x)));

  float eu = ut[(size_t)iu * DDIM + lane];
  float ep = it[(size_t)ip * DDIM + lane];
  float en = it[(size_t)ing * DDIM + lane];
  float rr = wave_sum(eu * eu + ep * ep + en * en);
  if (lane == 0) { sp_arr[b] = sp; rr_arr[b] = rr; }

  float n1 = fmaxf(sqrtf(wave_sum(cu * cu)), 1e-12f);
  float n2 = fmaxf(sqrtf(wave_sum(ue * ue)), 1e-12f);
  float d12 = wave_sum(cu * ue);
  z1u[(size_t)b * DDIM + lane] = f2bf(cu / n1);
  z2u[(size_t)b * DDIM + lane] = f2bf(ue / n2);
  if (lane == 0) pos_u[b] = d12 / (n1 * n2) * INV_TEMP;

  float m1 = fmaxf(sqrtf(wave_sum(ci * ci)), 1e-12f);
  float m2 = fmaxf(sqrtf(wave_sum(pe * pe)), 1e-12f);
  float e12 = wave_sum(ci * pe);
  z1i[(size_t)b * DDIM + lane] = f2bf(ci / m1);
  z2i[(size_t)b * DDIM + lane] = f2bf(pe / m2);
  if (lane == 0) pos_i[b] = e12 / (m1 * m2) * INV_TEMP;
}

// ---------------- InfoNCE via MFMA: wave = 16 rows x 1024-col chunk ------------------
__global__ __launch_bounds__(256) void infonce_kernel(const unsigned short* __restrict__ Z1u,
                                                      const unsigned short* __restrict__ Z2u,
                                                      const unsigned short* __restrict__ Z1i,
                                                      const unsigned short* __restrict__ Z2i,
                                                      float* __restrict__ rowpart_u,
                                                      float* __restrict__ rowpart_i) {
  const unsigned short* Z1 = blockIdx.z ? Z1i : Z1u;
  const unsigned short* Z2 = blockIdx.z ? Z2i : Z2u;
  float* rowpart = blockIdx.z ? rowpart_i : rowpart_u;
  int t = threadIdx.x;
  int wv = t >> 6, lane = t & 63;
  int i0 = (blockIdx.y * 4 + wv) * 16;   // wave's 16-row group (0..255 groups)
  int j0 = blockIdx.x * (BB / NCHUNK);   // chunk base (1024 cols)
  int m = lane & 15, q = lane >> 4;
  const unsigned short* ap = Z1 + (size_t)(i0 + m) * DDIM + q * 8;
  shortx8 a0 = *(const shortx8*)ap;
  shortx8 a1 = *(const shortx8*)(ap + 32);
  const unsigned short* bp = Z2 + (size_t)(j0 + m) * DDIM + q * 8;
  float rs[4] = {0.f, 0.f, 0.f, 0.f};
#pragma unroll 4
  for (int jt = 0; jt < (BB / NCHUNK) / 16; ++jt) {   // 64 j-tiles
    shortx8 b0 = *(const shortx8*)(bp + (size_t)jt * 16 * DDIM);
    shortx8 b1 = *(const shortx8*)(bp + (size_t)jt * 16 * DDIM + 32);
    floatx4 acc = {0.f, 0.f, 0.f, 0.f};
    acc = __builtin_amdgcn_mfma_f32_16x16x32_bf16(a0, b0, acc, 0, 0, 0);
    acc = __builtin_amdgcn_mfma_f32_16x16x32_bf16(a1, b1, acc, 0, 0, 0);
#pragma unroll
    for (int r = 0; r < 4; ++r) rs[r] += __expf(acc[r] * INV_TEMP);
  }
#pragma unroll
  for (int mm = 1; mm <= 8; mm <<= 1)
#pragma unroll
    for (int r = 0; r < 4; ++r) rs[r] += __shfl_xor(rs[r], mm, 64);
  if (m == 0) {
#pragma unroll
    for (int r = 0; r < 4; ++r)
      rowpart[(size_t)blockIdx.x * BB + i0 + q * 4 + r] = rs[r];
  }
}

// ---------------- finalize (inlines the NCHUNK rowpart reduction) ----------------
__global__ __launch_bounds__(256) void finalize_kernel(const float* __restrict__ rowpart_u,
                                                       const float* __restrict__ pos_u,
                                                       const float* __restrict__ rowpart_i,
                                                       const float* __restrict__ pos_i,
                                                       const float* __restrict__ sp_arr,
                                                       const float* __restrict__ rr_arr,
                                                       float* __restrict__ out) {
  int t = threadIdx.x;
  float su = 0.f, si = 0.f, sb = 0.f, sr = 0.f;
  for (int i = t; i < BB; i += 256) {
    float ru = 0.f, ri = 0.f;
#pragma unroll
    for (int jb = 0; jb < NCHUNK; ++jb) {
      ru += rowpart_u[(size_t)jb * BB + i];
      ri += rowpart_i[(size_t)jb * BB + i];
    }
    su += logf(ru) - pos_u[i];
    si += logf(ri) - pos_i[i];
    sb += sp_arr[i];
    sr += rr_arr[i];
  }
  su = wave_sum(su);
  si = wave_sum(si);
  sb = wave_sum(sb);
  sr = wave_sum(sr);
  __shared__ float sh[16];
  int lane = t & 63, wid = t >> 6;
  if (lane == 0) { sh[wid] = su; sh[4 + wid] = si; sh[8 + wid] = sb; sh[12 + wid] = sr; }
  __syncthreads();
  if (t == 0) {
    float SU = sh[0] + sh[1] + sh[2] + sh[3];
    float SI = sh[4] + sh[5] + sh[6] + sh[7];
    float SB = sh[8] + sh[9] + sh[10] + sh[11];
    float SR = sh[12] + sh[13] + sh[14] + sh[15];
    out[0] = SB * (1.f / BB);
    out[1] = 1e-4f * 0.5f * SR * (1.f / BB);
    out[2] = 0.2f * ((SU + SI) * (1.f / BB));
  }
}

extern "C" void kernel_launch(void* const* d_in, const int* in_sizes, int n_in,
                              void* d_out, int out_size, void* d_ws, size_t ws_size,
                              hipStream_t stream) {
  const float* user_table = (const float*)d_in[0];
  const float* item_table = (const float*)d_in[1];
  const float* noise      = (const float*)d_in[3];
  const int*   edge_src   = (const int*)d_in[4];
  const int*   edge_dst   = (const int*)d_in[5];
  const int*   user       = (const int*)d_in[6];
  const int*   positive   = (const int*)d_in[7];
  const int*   negative   = (const int*)d_in[8];
  const int E2 = in_sizes[2];  // 2,000,000

  const int eh = E2 >> 1;
  const int nbu = (eh + EPB - 1) / EPB;            // 245
  const int nbi = (E2 - eh + EPB - 1) / EPB;       // 245
  const int nbp = nbu + nbi;                       // 490

  char* w = (char*)d_ws;
  auto alloc = [&](size_t bytes) -> void* {
    void* p = (void*)w;
    w += (bytes + 255) & ~(size_t)255;
    return p;
  };
  int*   rtot     = (int*)alloc((size_t)NRANGE * 4);
  int*   bcnt     = (int*)alloc((size_t)NRANGE * nbp * 4);
  int*   boff     = (int*)alloc((size_t)NRANGE * nbp * 4);
  int*   row_ptr  = (int*)alloc((size_t)(NNODE + 1) * 4);
  int*   counts   = (int*)alloc((size_t)NNODE * 4);
  int*   csr_dst  = (int*)alloc((size_t)(E2 + 64) * 4);   // +64 pad: unpredicated chunk load
  unsigned* binned = (unsigned*)alloc((size_t)E2 * 4);
  unsigned char* y_init = (unsigned char*)alloc((size_t)(NNODE + 1) * DDIM);
  unsigned char* yb0    = (unsigned char*)alloc((size_t)(NNODE + 1) * DDIM);
  unsigned char* yb1    = (unsigned char*)alloc((size_t)(NNODE + 1) * DDIM);
  unsigned char* yb2    = (unsigned char*)alloc((size_t)(NNODE + 1) * DDIM);
  unsigned short* z1u    = (unsigned short*)alloc((size_t)BB * DDIM * 2);
  unsigned short* z2u    = (unsigned short*)alloc((size_t)BB * DDIM * 2);
  unsigned short* z1i    = (unsigned short*)alloc((size_t)BB * DDIM * 2);
  unsigned short* z2i    = (unsigned short*)alloc((size_t)BB * DDIM * 2);
  float* pos_u    = (float*)alloc((size_t)BB * 4);
  float* pos_i    = (float*)alloc((size_t)BB * 4);
  float* sp_arr   = (float*)alloc((size_t)BB * 4);
  float* rr_arr   = (float*)alloc((size_t)BB * 4);
  float* rowpart_u = (float*)alloc((size_t)NCHUNK * BB * 4);
  float* rowpart_i = (float*)alloc((size_t)NCHUNK * BB * 4);

  pcount_kernel<<<nbp, 256, 0, stream>>>(edge_src, bcnt, E2, nbu, nbp);
  pscan_kernel<<<NRANGE, 256, 0, stream>>>(bcnt, boff, rtot, nbp);
  pscatter_kernel<<<nbp, 512, 0, stream>>>(edge_src, edge_dst, boff, rtot, binned,
                                           E2, nbu, nbp);
  place_kernel<<<NRANGE, 512, 0, stream>>>(binned, rtot, row_ptr, counts, csr_dst,
                                           user_table, item_table, y_init, E2);
  const int spmm_waves = NNODE / 4 + 1;         // 4 rows per wave + dummy-row wave
  const int spmm_blocks = (spmm_waves + 3) / 4; // 4 waves per 256-thread block
  spmm_kernel<<<spmm_blocks, 256, 0, stream>>>(y_init, row_ptr, csr_dst, counts,
                                               noise + (size_t)0 * NNODE * DDIM, yb0);
  spmm_kernel<<<spmm_blocks, 256, 0, stream>>>(yb0, row_ptr, csr_dst, counts,
                                               noise + (size_t)1 * NNODE * DDIM, yb1);
  spmm_kernel<<<spmm_blocks, 256, 0, stream>>>(yb1, row_ptr, csr_dst, counts,
                                               noise + (size_t)2 * NNODE * DDIM, yb2);
  batch_kernel<<<BB / 4, 256, 0, stream>>>(yb0, yb1, yb2, user_table, item_table, counts,
                                           user, positive, negative,
                                           z1u, z2u, z1i, z2i, pos_u, pos_i, sp_arr, rr_arr);
  dim3 ig(NCHUNK, BB / 64, 2);   // 4 chunks x 64 blocks.y (4 i-groups each) x {u,i}
  infonce_kernel<<<ig, 256, 0, stream>>>(z1u, z2u, z1i, z2i, rowpart_u, rowpart_i);
  finalize_kernel<<<1, 256, 0, stream>>>(rowpart_u, pos_u, rowpart_i, pos_i,
                                         sp_arr, rr_arr, (float*)d_out);
}

// Round 14
// 329.903 us; speedup vs baseline: 1.2470x; 1.0007x over previous
//
#include <hip/hip_runtime.h>
#include <hip/hip_bf16.h>
#include <hip/hip_fp8.h>
#include <math.h>

#define UCNT 50000
#define ICNT 25000
#define NNODE 75000
#define DDIM 64
#define BB 4096
#define EPS_C 0.2f
#define INV_TEMP 5.0f
#define NCHUNK 4            // j-chunks in infonce (1024 cols each)

#define NRANGE 293          // 256-node ranges
#define RB_U 196            // user-half ranges (0..195; range 195 shared w/ items)
#define RB_I 98             // item-half ranges (195..292 -> rel 0..97)
#define GOFF_I 195
#define EPB 4096            // edges per partition block (both halves)
#define YS 64.0f            // fp8 y scale (keeps elements in e4m3 normal range)
#define YSI (1.0f / 64.0f)

typedef float floatx4 __attribute__((ext_vector_type(4)));
typedef float floatx2 __attribute__((ext_vector_type(2)));
typedef short shortx8 __attribute__((ext_vector_type(8)));

__device__ __forceinline__ float wave_sum(float x) {
#pragma unroll
  for (int m = 32; m >= 1; m >>= 1) x += __shfl_xor(x, m, 64);
  return x;
}

__device__ __forceinline__ unsigned short f2bf(float f) {   // RNE
  unsigned u = __float_as_uint(f);
  u += 0x7fffu + ((u >> 16) & 1u);
  return (unsigned short)(u >> 16);
}
// HW fp8 (OCP e4m3 on gfx950) encode pair / decode single
__device__ __forceinline__ unsigned enc_pk4(float a, float b, float c, float d) {
  int w = 0;
  w = __builtin_amdgcn_cvt_pk_fp8_f32(a, b, w, false);   // bytes 0,1
  w = __builtin_amdgcn_cvt_pk_fp8_f32(c, d, w, true);    // bytes 2,3
  return (unsigned)w;
}
__device__ __forceinline__ float fp8dec1(unsigned char b) {
  return __builtin_amdgcn_cvt_f32_fp8((int)b, 0);
}

// ---------------- pcount: per (stripe-block, range) histogram -> bcnt column ---------
__global__ __launch_bounds__(256) void pcount_kernel(const int* __restrict__ src,
                                                     int* __restrict__ bcnt,
                                                     int ne, int nbu, int nbp) {
  __shared__ int qc[RB_U];
  int t = threadIdx.x;
  int b = blockIdx.x;
  int eh = ne >> 1;
  bool isU = b < nbu;
  int base = isU ? b * EPB : eh + (b - nbu) * EPB;
  int lim = min(base + EPB, isU ? eh : ne);
  int RB = isU ? RB_U : RB_I;
  int goff = isU ? 0 : GOFF_I;
  for (int i = t; i < RB; i += 256) qc[i] = 0;
  __syncthreads();
  for (int i = base + t; i < lim; i += 256) {
    int s = __builtin_nontemporal_load(src + i);
    atomicAdd(&qc[(s >> 8) - goff], 1);
  }
  __syncthreads();
  for (int r = t; r < NRANGE; r += 256) {
    int rel = r - goff;
    int v = (rel >= 0 && rel < RB) ? qc[rel] : 0;
    bcnt[(size_t)r * nbp + b] = v;
  }
}

// ---------------- pscan: per range, local exclusive scan over block columns ----------
__global__ __launch_bounds__(256) void pscan_kernel(const int* __restrict__ bcnt,
                                                    int* __restrict__ boff,
                                                    int* __restrict__ rtot, int nbp) {
  __shared__ int s0[512], s1[512];
  int r = blockIdx.x, t = threadIdx.x;
  for (int j = t; j < 512; j += 256) s0[j] = (j < nbp) ? bcnt[(size_t)r * nbp + j] : 0;
  __syncthreads();
  int* a = s0;
  int* bf = s1;
  for (int off = 1; off < 512; off <<= 1) {
    for (int j = t; j < 512; j += 256) bf[j] = a[j] + ((j >= off) ? a[j - off] : 0);
    __syncthreads();
    int* tmp = a; a = bf; bf = tmp;
  }
  for (int j = t; j < nbp; j += 256)
    boff[(size_t)r * nbp + j] = a[j] - bcnt[(size_t)r * nbp + j];
  if (t == 0) rtot[r] = a[511];
}

// ---- inline exclusive scan of rtot[NRANGE] -> cb[] (LDS), nthr threads --------------
__device__ __forceinline__ void scan_rtot(const int* __restrict__ rtot,
                                          int* s0, int* s1, int* cb, int t, int nthr) {
  for (int j = t; j < 512; j += nthr) s0[j] = (j < NRANGE) ? rtot[j] : 0;
  __syncthreads();
  int* a = s0;
  int* bf = s1;
  for (int off = 1; off < 512; off <<= 1) {
    for (int j = t; j < 512; j += nthr) bf[j] = a[j] + ((j >= off) ? a[j - off] : 0);
    __syncthreads();
    int* tmp = a; a = bf; bf = tmp;
  }
  for (int j = t; j < NRANGE; j += nthr) cb[j] = a[j] - rtot[j];
  __syncthreads();
}

// ---------------- pscatter: deterministic binning into u32 (srcLow8 | dst) -----------
// 512 threads: halves the serial stripe-loop trip count; cbase inline from rtot.
__global__ __launch_bounds__(512) void pscatter_kernel(const int* __restrict__ src,
                                                       const int* __restrict__ dst,
                                                       const int* __restrict__ boff,
                                                       const int* __restrict__ rtot,
                                                       unsigned* __restrict__ binned,
                                                       int ne, int nbu, int nbp) {
  __shared__ int qc[RB_U];
  __shared__ int s0[512], s1[512], cb[NRANGE];
  int t = threadIdx.x;
  int b = blockIdx.x;
  for (int i = t; i < RB_U; i += 512) qc[i] = 0;
  scan_rtot(rtot, s0, s1, cb, t, 512);  // also covers the qc-zero sync
  int eh = ne >> 1;
  bool isU = b < nbu;
  int base = isU ? b * EPB : eh + (b - nbu) * EPB;
  int lim = min(base + EPB, isU ? eh : ne);
  int goff = isU ? 0 : GOFF_I;
  for (int i = base + t; i < lim; i += 512) {
    int s = __builtin_nontemporal_load(src + i);
    int d = __builtin_nontemporal_load(dst + i);
    int rb = (s >> 8) - goff;
    int pos = atomicAdd(&qc[rb], 1);
    int rg = rb + goff;
    int g = cb[rg] + boff[(size_t)rg * nbp + b] + pos;
    binned[g] = ((unsigned)(s & 255) << 24) | (unsigned)d;   // dst < 2^24
  }
}

// ---------------- place: one block per range -> row_ptr, counts, csr + prescale ------
// 512 threads: histogram + scatter passes halve their trip counts. Node-scan section
// guarded to t<256. Fused prescale (y_init encode) at the end.
__global__ __launch_bounds__(512) void place_kernel(
    const unsigned* __restrict__ binned, const int* __restrict__ rtot,
    int* __restrict__ row_ptr, int* __restrict__ counts,
    int* __restrict__ csr_dst,
    const float* __restrict__ ut, const float* __restrict__ it,
    unsigned char* __restrict__ y, int ne) {
  __shared__ int cnt[256], cur[256], ws[4], wo[4];
  __shared__ int s0[512], s1[512], cb[NRANGE];
  int t = threadIdx.x;
  int b = blockIdx.x;
  int r0 = b << 8;
  int n = r0 + t;
  if (t < 256) cnt[t] = 0;
  scan_rtot(rtot, s0, s1, cb, t, 512);  // also covers the cnt-zero sync
  int seg0 = cb[b];
  int seg1 = (b == NRANGE - 1) ? ne : cb[b + 1];
  if (b == NRANGE - 1 && t == 0) row_ptr[NNODE] = ne;
  for (int j = seg0 + t; j < seg1; j += 512)
    atomicAdd(&cnt[binned[j] >> 24], 1);
  __syncthreads();
  int lane = t & 63, wid = t >> 6;
  int c = (t < 256) ? cnt[t] : 0;
  int v = c;
#pragma unroll
  for (int d = 1; d < 64; d <<= 1) {
    int u = __shfl_up(v, d, 64);
    if (lane >= d) v += u;
  }
  if (lane == 63 && wid < 4) ws[wid] = v;
  __syncthreads();
  if (t == 0) {
    int run = 0;
    for (int k = 0; k < 4; ++k) { wo[k] = run; run += ws[k]; }
  }
  __syncthreads();
  if (t < 256) {
    int excl = v - c + wo[wid];
    if (n < NNODE) {
      row_ptr[n] = seg0 + excl;
      counts[n] = c;
    }
    cur[t] = excl;
  }
  __syncthreads();
  for (int j = seg0 + t; j < seg1; j += 512) {
    unsigned e = binned[j];
    int off = atomicAdd(&cur[e >> 24], 1);
    csr_dst[seg0 + off] = (int)(e & 0xFFFFFFu);
  }
  // ---- fused prescale: y[n] = fp8(table[n] * rsqrt(max(deg,1)) * YS) ----
  if (t < 256 && n <= NNODE) {
    unsigned ow[16];
    if (n == NNODE) {
#pragma unroll
      for (int k = 0; k < 16; ++k) ow[k] = 0u;       // dummy zero row
    } else {
      float sc = rsqrtf(fmaxf((float)c, 1.f)) * YS;
      const float* srcp = (n < UCNT) ? (ut + (size_t)n * DDIM)
                                     : (it + (size_t)(n - UCNT) * DDIM);
#pragma unroll
      for (int k = 0; k < 16; ++k) {
        float4 vv = ((const float4*)srcp)[k];
        ow[k] = enc_pk4(vv.x * sc, vv.y * sc, vv.z * sc, vv.w * sc);
      }
    }
    uint4* yp = (uint4*)(y + (size_t)n * DDIM);
#pragma unroll
    for (int k = 0; k < 4; ++k) yp[k] = *(const uint4*)&ow[k * 4];
  }
}

// ---- gather helpers: 8 edge-groups x 8 dim-slices; issue all, then consume ----------
__device__ __forceinline__ void gather_issue(const unsigned char* __restrict__ yb,
                                             int d, int nit, int g, unsigned voff,
                                             uint2* pk) {
#pragma unroll
  for (int j = 0; j < 8; ++j) {
    if (j < nit) {
      int dj = __shfl(d, j * 8 + g, 64);
      pk[j] = *(const uint2*)(yb + (((unsigned)dj << 6) + voff));   // 32-bit voffset
    }
  }
}
__device__ __forceinline__ void gather_acc(const uint2* pk, int nit,
                                           floatx2& a0, floatx2& a1,
                                           floatx2& a2, floatx2& a3) {
#pragma unroll
  for (int j = 0; j < 8; ++j) {
    if (j < nit) {
      a0 += __builtin_amdgcn_cvt_pk_f32_fp8(pk[j].x, 0);
      a1 += __builtin_amdgcn_cvt_pk_f32_fp8(pk[j].x, 1);
      a2 += __builtin_amdgcn_cvt_pk_f32_fp8(pk[j].y, 0);
      a3 += __builtin_amdgcn_cvt_pk_f32_fp8(pk[j].y, 1);
    }
  }
}

// ---------------- SpMM: 4 adjacent rows per wave, staged select-reduce ---------------
// csr loads are PLAIN (cached) — csr_dst is re-read by all 3 layer passes and fits
// in aggregate L2; the index load is the first leg of the dependent gather chain,
// so L2-residency across passes cuts its exposed latency. Noise stays nontemporal
// (distinct 19 MB region per pass, never reused).
__global__ __launch_bounds__(256) void spmm_kernel(const unsigned char* __restrict__ y_in,
                                                   const int* __restrict__ row_ptr,
                                                   const int* __restrict__ csr_dst,
                                                   const int* __restrict__ counts,
                                                   const float* __restrict__ noise,
                                                   unsigned char* __restrict__ y_out) {
  const int NW = NNODE / 4;   // 18750 full waves
  int wv = __builtin_amdgcn_readfirstlane(blockIdx.x * 4 + (threadIdx.x >> 6));
  int lane = threadIdx.x & 63;
  if (wv > NW) return;
  int g = lane >> 3, l8 = lane & 7;
  unsigned voff = (unsigned)(l8 * 8);
  if (wv == NW) {                     // keep dummy zero row alive in the output buffer
    if (g == 0) {
      uint2 z; z.x = 0u; z.y = 0u;
      *(uint2*)(y_out + (size_t)NNODE * DDIM + voff) = z;
    }
    return;
  }
  int r0 = wv * 4;
  int b0 = row_ptr[r0];               // uniform -> s_load
  int b1 = row_ptr[r0 + 1];
  int b2 = row_ptr[r0 + 2];
  int b3 = row_ptr[r0 + 3];
  int b4 = row_ptr[r0 + 4];
  // prefetch noise rows (consumed in epilogue, hidden under gathers)
  floatx4 nv[4][2];
#pragma unroll
  for (int r = 0; r < 4; ++r) {
    nv[r][0] = __builtin_nontemporal_load((const floatx4*)(noise + (size_t)(r0 + r) * DDIM + l8 * 8));
    nv[r][1] = __builtin_nontemporal_load((const floatx4*)(noise + (size_t)(r0 + r) * DDIM + l8 * 8 + 4));
  }
  float scr0 = rsqrtf(fmaxf((float)counts[r0], 1.f));
  float scr1 = rsqrtf(fmaxf((float)counts[r0 + 1], 1.f));
  float scr2 = rsqrtf(fmaxf((float)counts[r0 + 2], 1.f));
  float scr3 = rsqrtf(fmaxf((float)counts[r0 + 3], 1.f));

  int c0 = min(b1 - b0, 64), c1 = min(b2 - b1, 64);
  int c2 = min(b3 - b2, 64), c3 = min(b4 - b3, 64);
  int nit0 = (c0 + 7) >> 3, nit1 = (c1 + 7) >> 3;
  int nit2 = (c2 + 7) >> 3, nit3 = (c3 + 7) >> 3;
  int d0 = csr_dst[b0 + lane];        // plain loads: L2-resident across passes
  int d1 = csr_dst[b1 + lane];
  int d2 = csr_dst[b2 + lane];
  int d3 = csr_dst[b3 + lane];
  d0 = (lane < c0) ? d0 : NNODE;      // lanes past cnt -> dummy zero row
  d1 = (lane < c1) ? d1 : NNODE;
  d2 = (lane < c2) ? d2 : NNODE;
  d3 = (lane < c3) ? d3 : NNODE;

  floatx2 a0[4] = {{0.f,0.f},{0.f,0.f},{0.f,0.f},{0.f,0.f}};
  floatx2 a1[4] = {{0.f,0.f},{0.f,0.f},{0.f,0.f},{0.f,0.f}};
  floatx2 a2[4] = {{0.f,0.f},{0.f,0.f},{0.f,0.f},{0.f,0.f}};
  floatx2 a3[4] = {{0.f,0.f},{0.f,0.f},{0.f,0.f},{0.f,0.f}};
  {
    uint2 p0[8], p1[8], p2[8], p3[8];
    gather_issue(y_in, d0, nit0, g, voff, p0);   // all 4 rows' loads in flight
    gather_issue(y_in, d1, nit1, g, voff, p1);
    gather_issue(y_in, d2, nit2, g, voff, p2);
    gather_issue(y_in, d3, nit3, g, voff, p3);
    gather_acc(p0, nit0, a0[0], a0[1], a0[2], a0[3]);
    gather_acc(p1, nit1, a1[0], a1[1], a1[2], a1[3]);
    gather_acc(p2, nit2, a2[0], a2[1], a2[2], a2[3]);
    gather_acc(p3, nit3, a3[0], a3[1], a3[2], a3[3]);
  }
  // rare deg>64 tails, one loop per row
  for (int e0 = b0 + 64; e0 < b1; e0 += 64) {
    int cc = min(b1 - e0, 64); int nn = (cc + 7) >> 3;
    int dd = csr_dst[e0 + lane];
    dd = (lane < cc) ? dd : NNODE;
    uint2 pp[8];
    gather_issue(y_in, dd, nn, g, voff, pp);
    gather_acc(pp, nn, a0[0], a0[1], a0[2], a0[3]);
  }
  for (int e0 = b1 + 64; e0 < b2; e0 += 64) {
    int cc = min(b2 - e0, 64); int nn = (cc + 7) >> 3;
    int dd = csr_dst[e0 + lane];
    dd = (lane < cc) ? dd : NNODE;
    uint2 pp[8];
    gather_issue(y_in, dd, nn, g, voff, pp);
    gather_acc(pp, nn, a1[0], a1[1], a1[2], a1[3]);
  }
  for (int e0 = b2 + 64; e0 < b3; e0 += 64) {
    int cc = min(b3 - e0, 64); int nn = (cc + 7) >> 3;
    int dd = csr_dst[e0 + lane];
    dd = (lane < cc) ? dd : NNODE;
    uint2 pp[8];
    gather_issue(y_in, dd, nn, g, voff, pp);
    gather_acc(pp, nn, a2[0], a2[1], a2[2], a2[3]);
  }
  for (int e0 = b3 + 64; e0 < b4; e0 += 64) {
    int cc = min(b4 - e0, 64); int nn = (cc + 7) >> 3;
    int dd = csr_dst[e0 + lane];
    dd = (lane < cc) ? dd : NNODE;
    uint2 pp[8];
    gather_issue(y_in, dd, nn, g, voff, pp);
    gather_acc(pp, nn, a3[0], a3[1], a3[2], a3[3]);
  }

  float A0[8] = {a0[0][0], a0[0][1], a0[1][0], a0[1][1], a0[2][0], a0[2][1], a0[3][0], a0[3][1]};
  float A1[8] = {a1[0][0], a1[0][1], a1[1][0], a1[1][1], a1[2][0], a1[2][1], a1[3][0], a1[3][1]};
  float A2[8] = {a2[0][0], a2[0][1], a2[1][0], a2[1][1], a2[2][0], a2[2][1], a2[3][0], a2[3][1]};
  float A3[8] = {a3[0][0], a3[0][1], a3[1][0], a3[1][1], a3[2][0], a3[2][1], a3[3][0], a3[3][1]};

  int gr = g & 3;
  bool hi2 = (gr & 2) != 0, hi1 = (gr & 1) != 0;

  // round 1: xor 32 — plain add, all 4 rows (values now depend on g&3 only)
#pragma unroll
  for (int k = 0; k < 8; ++k) {
    A0[k] += __shfl_xor(A0[k], 32, 64);
    A1[k] += __shfl_xor(A1[k], 32, 64);
    A2[k] += __shfl_xor(A2[k], 32, 64);
    A3[k] += __shfl_xor(A3[k], 32, 64);
  }
  // round 2: xor 16 — exchange ALL rows, keep own[r]+partner[r] for rows with
  // bit1(r) == bit1(class). Classes {0,1} keep rows {0,1}; {2,3} keep rows {2,3}.
  float B0[8], B1[8];
#pragma unroll
  for (int k = 0; k < 8; ++k) {
    float r0v = __shfl_xor(A0[k], 16, 64);
    float r1v = __shfl_xor(A1[k], 16, 64);
    float r2v = __shfl_xor(A2[k], 16, 64);
    float r3v = __shfl_xor(A3[k], 16, 64);
    B0[k] = hi2 ? (A2[k] + r2v) : (A0[k] + r0v);
    B1[k] = hi2 ? (A3[k] + r3v) : (A1[k] + r1v);
  }
  // round 3: xor 8 — exchange both rows, keep the one matching bit0(class)
  float C[8];
#pragma unroll
  for (int k = 0; k < 8; ++k) {
    float s0 = __shfl_xor(B0[k], 8, 64);
    float s1 = __shfl_xor(B1[k], 8, 64);
    C[k] = hi1 ? (B1[k] + s1) : (B0[k] + s0);
  }

  // select this group's noise slices + scale (row r0+gr)
  float sn[8];
#pragma unroll
  for (int k = 0; k < 4; ++k) {
    float lo = hi1 ? nv[1][0][k] : nv[0][0][k];
    float hi = hi1 ? nv[3][0][k] : nv[2][0][k];
    sn[k] = hi2 ? hi : lo;
    float lo2 = hi1 ? nv[1][1][k] : nv[0][1][k];
    float hi2v = hi1 ? nv[3][1][k] : nv[2][1][k];
    sn[4 + k] = hi2 ? hi2v : lo2;
  }
  float scr = hi2 ? (hi1 ? scr3 : scr2) : (hi1 ? scr1 : scr0);

  float ss = 0.f;
#pragma unroll
  for (int k = 0; k < 8; ++k) ss += sn[k] * sn[k];
#pragma unroll
  for (int m = 1; m <= 4; m <<= 1) ss += __shfl_xor(ss, m, 64);  // within 8-lane group
  float inv = EPS_C / fmaxf(sqrtf(ss), 1e-12f);

  float ov[8];
#pragma unroll
  for (int k = 0; k < 8; ++k) {
    float x = C[k] * scr * YSI;
    float sgn = (x > 0.f) ? 1.f : ((x < 0.f) ? -1.f : 0.f);
    ov[k] = (x + sgn * sn[k] * inv) * scr * YS;
  }
  if (g < 4) {                          // groups 0..3 store rows r0..r0+3
    uint2 o;
    o.x = enc_pk4(ov[0], ov[1], ov[2], ov[3]);
    o.y = enc_pk4(ov[4], ov[5], ov[6], ov[7]);
    *(uint2*)(y_out + (((unsigned)(r0 + gr)) << 6) + voff) = o;
  }
}

// ---------------- batch gather: BPR, reg, bf16 normalized InfoNCE inputs -------------
__global__ __launch_bounds__(256) void batch_kernel(
    const unsigned char* __restrict__ yb0, const unsigned char* __restrict__ yb1,
    const unsigned char* __restrict__ yb2,
    const float* __restrict__ ut, const float* __restrict__ it,
    const int* __restrict__ counts,
    const int* __restrict__ user, const int* __restrict__ pos, const int* __restrict__ neg,
    unsigned short* __restrict__ z1u, unsigned short* __restrict__ z2u,
    unsigned short* __restrict__ z1i, unsigned short* __restrict__ z2i,
    float* __restrict__ pos_u, float* __restrict__ pos_i,
    float* __restrict__ sp_arr, float* __restrict__ rr_arr) {
  int wave = blockIdx.x * (blockDim.x >> 6) + (threadIdx.x >> 6);
  int lane = threadIdx.x & 63;
  if (wave >= BB) return;
  int b = wave;
  int iu = user[b], ip = pos[b], ing = neg[b];
  float s_u = sqrtf(fmaxf((float)counts[iu], 1.f)) * YSI;
  float s_p = sqrtf(fmaxf((float)counts[UCNT + ip], 1.f)) * YSI;
  float s_n = sqrtf(fmaxf((float)counts[UCNT + ing], 1.f)) * YSI;
  size_t ru = (size_t)iu * DDIM + lane;
  size_t rp = (size_t)(UCNT + ip) * DDIM + lane;
  size_t rn = (size_t)(UCNT + ing) * DDIM + lane;
  float cu = fp8dec1(yb0[ru]) * s_u;        // x_cl user row
  float ci = fp8dec1(yb0[rp]) * s_p;        // x_cl positive-item row
  float ue = (cu + (fp8dec1(yb1[ru]) + fp8dec1(yb2[ru])) * s_u) * (1.f / 3.f);
  float pe = (ci + (fp8dec1(yb1[rp]) + fp8dec1(yb2[rp])) * s_p) * (1.f / 3.f);
  float ne = (fp8dec1(yb0[rn]) + fp8dec1(yb1[rn]) + fp8dec1(yb2[rn])) * s_n * (1.f / 3.f);

  float ps = wave_sum(ue * pe);
  float ns = wave_sum(ue * ne);
  float x = ns - ps;
  float sp = fmaxf(x, 0.f) + log1pf(expf(-fabsf(x)));

  float eu = ut[(size_t)iu * DDIM + lane];
  float ep = it[(size_t)ip * DDIM + lane];
  float en = it[(size_t)ing * DDIM + lane];
  float rr = wave_sum(eu * eu + ep * ep + en * en);
  if (lane == 0) { sp_arr[b] = sp; rr_arr[b] = rr; }

  float n1 = fmaxf(sqrtf(wave_sum(cu * cu)), 1e-12f);
  float n2 = fmaxf(sqrtf(wave_sum(ue * ue)), 1e-12f);
  float d12 = wave_sum(cu * ue);
  z1u[(size_t)b * DDIM + lane] = f2bf(cu / n1);
  z2u[(size_t)b * DDIM + lane] = f2bf(ue / n2);
  if (lane == 0) pos_u[b] = d12 / (n1 * n2) * INV_TEMP;

  float m1 = fmaxf(sqrtf(wave_sum(ci * ci)), 1e-12f);
  float m2 = fmaxf(sqrtf(wave_sum(pe * pe)), 1e-12f);
  float e12 = wave_sum(ci * pe);
  z1i[(size_t)b * DDIM + lane] = f2bf(ci / m1);
  z2i[(size_t)b * DDIM + lane] = f2bf(pe / m2);
  if (lane == 0) pos_i[b] = e12 / (m1 * m2) * INV_TEMP;
}

// ---------------- InfoNCE via MFMA: wave = 16 rows x 1024-col chunk ------------------
__global__ __launch_bounds__(256) void infonce_kernel(const unsigned short* __restrict__ Z1u,
                                                      const unsigned short* __restrict__ Z2u,
                                                      const unsigned short* __restrict__ Z1i,
                                                      const unsigned short* __restrict__ Z2i,
                                                      float* __restrict__ rowpart_u,
                                                      float* __restrict__ rowpart_i) {
  const unsigned short* Z1 = blockIdx.z ? Z1i : Z1u;
  const unsigned short* Z2 = blockIdx.z ? Z2i : Z2u;
  float* rowpart = blockIdx.z ? rowpart_i : rowpart_u;
  int t = threadIdx.x;
  int wv = t >> 6, lane = t & 63;
  int i0 = (blockIdx.y * 4 + wv) * 16;   // wave's 16-row group (0..255 groups)
  int j0 = blockIdx.x * (BB / NCHUNK);   // chunk base (1024 cols)
  int m = lane & 15, q = lane >> 4;
  const unsigned short* ap = Z1 + (size_t)(i0 + m) * DDIM + q * 8;
  shortx8 a0 = *(const shortx8*)ap;
  shortx8 a1 = *(const shortx8*)(ap + 32);
  const unsigned short* bp = Z2 + (size_t)(j0 + m) * DDIM + q * 8;
  float rs[4] = {0.f, 0.f, 0.f, 0.f};
#pragma unroll 4
  for (int jt = 0; jt < (BB / NCHUNK) / 16; ++jt) {   // 64 j-tiles
    shortx8 b0 = *(const shortx8*)(bp + (size_t)jt * 16 * DDIM);
    shortx8 b1 = *(const shortx8*)(bp + (size_t)jt * 16 * DDIM + 32);
    floatx4 acc = {0.f, 0.f, 0.f, 0.f};
    acc = __builtin_amdgcn_mfma_f32_16x16x32_bf16(a0, b0, acc, 0, 0, 0);
    acc = __builtin_amdgcn_mfma_f32_16x16x32_bf16(a1, b1, acc, 0, 0, 0);
#pragma unroll
    for (int r = 0; r < 4; ++r) rs[r] += __expf(acc[r] * INV_TEMP);
  }
#pragma unroll
  for (int mm = 1; mm <= 8; mm <<= 1)
#pragma unroll
    for (int r = 0; r < 4; ++r) rs[r] += __shfl_xor(rs[r], mm, 64);
  if (m == 0) {
#pragma unroll
    for (int r = 0; r < 4; ++r)
      rowpart[(size_t)blockIdx.x * BB + i0 + q * 4 + r] = rs[r];
  }
}

// ---------------- finalize (inlines the NCHUNK rowpart reduction) ----------------
__global__ __launch_bounds__(256) void finalize_kernel(const float* __restrict__ rowpart_u,
                                                       const float* __restrict__ pos_u,
                                                       const float* __restrict__ rowpart_i,
                                                       const float* __restrict__ pos_i,
                                                       const float* __restrict__ sp_arr,
                                                       const float* __restrict__ rr_arr,
                                                       float* __restrict__ out) {
  int t = threadIdx.x;
  float su = 0.f, si = 0.f, sb = 0.f, sr = 0.f;
  for (int i = t; i < BB; i += 256) {
    float ru = 0.f, ri = 0.f;
#pragma unroll
    for (int jb = 0; jb < NCHUNK; ++jb) {
      ru += rowpart_u[(size_t)jb * BB + i];
      ri += rowpart_i[(size_t)jb * BB + i];
    }
    su += logf(ru) - pos_u[i];
    si += logf(ri) - pos_i[i];
    sb += sp_arr[i];
    sr += rr_arr[i];
  }
  su = wave_sum(su);
  si = wave_sum(si);
  sb = wave_sum(sb);
  sr = wave_sum(sr);
  __shared__ float sh[16];
  int lane = t & 63, wid = t >> 6;
  if (lane == 0) { sh[wid] = su; sh[4 + wid] = si; sh[8 + wid] = sb; sh[12 + wid] = sr; }
  __syncthreads();
  if (t == 0) {
    float SU = sh[0] + sh[1] + sh[2] + sh[3];
    float SI = sh[4] + sh[5] + sh[6] + sh[7];
    float SB = sh[8] + sh[9] + sh[10] + sh[11];
    float SR = sh[12] + sh[13] + sh[14] + sh[15];
    out[0] = SB * (1.f / BB);
    out[1] = 1e-4f * 0.5f * SR * (1.f / BB);
    out[2] = 0.2f * ((SU + SI) * (1.f / BB));
  }
}

extern "C" void kernel_launch(void* const* d_in, const int* in_sizes, int n_in,
                              void* d_out, int out_size, void* d_ws, size_t ws_size,
                              hipStream_t stream) {
  const float* user_table = (const float*)d_in[0];
  const float* item_table = (const float*)d_in[1];
  const float* noise      = (const float*)d_in[3];
  const int*   edge_src   = (const int*)d_in[4];
  const int*   edge_dst   = (const int*)d_in[5];
  const int*   user       = (const int*)d_in[6];
  const int*   positive   = (const int*)d_in[7];
  const int*   negative   = (const int*)d_in[8];
  const int E2 = in_sizes[2];  // 2,000,000

  const int eh = E2 >> 1;
  const int nbu = (eh + EPB - 1) / EPB;            // 245
  const int nbi = (E2 - eh + EPB - 1) / EPB;       // 245
  const int nbp = nbu + nbi;                       // 490

  char* w = (char*)d_ws;
  auto alloc = [&](size_t bytes) -> void* {
    void* p = (void*)w;
    w += (bytes + 255) & ~(size_t)255;
    return p;
  };
  int*   rtot     = (int*)alloc((size_t)NRANGE * 4);
  int*   bcnt     = (int*)alloc((size_t)NRANGE * nbp * 4);
  int*   boff     = (int*)alloc((size_t)NRANGE * nbp * 4);
  int*   row_ptr  = (int*)alloc((size_t)(NNODE + 1) * 4);
  int*   counts   = (int*)alloc((size_t)NNODE * 4);
  int*   csr_dst  = (int*)alloc((size_t)(E2 + 64) * 4);   // +64 pad: unpredicated chunk load
  unsigned* binned = (unsigned*)alloc((size_t)E2 * 4);
  unsigned char* y_init = (unsigned char*)alloc((size_t)(NNODE + 1) * DDIM);
  unsigned char* yb0    = (unsigned char*)alloc((size_t)(NNODE + 1) * DDIM);
  unsigned char* yb1    = (unsigned char*)alloc((size_t)(NNODE + 1) * DDIM);
  unsigned char* yb2    = (unsigned char*)alloc((size_t)(NNODE + 1) * DDIM);
  unsigned short* z1u    = (unsigned short*)alloc((size_t)BB * DDIM * 2);
  unsigned short* z2u    = (unsigned short*)alloc((size_t)BB * DDIM * 2);
  unsigned short* z1i    = (unsigned short*)alloc((size_t)BB * DDIM * 2);
  unsigned short* z2i    = (unsigned short*)alloc((size_t)BB * DDIM * 2);
  float* pos_u    = (float*)alloc((size_t)BB * 4);
  float* pos_i    = (float*)alloc((size_t)BB * 4);
  float* sp_arr   = (float*)alloc((size_t)BB * 4);
  float* rr_arr   = (float*)alloc((size_t)BB * 4);
  float* rowpart_u = (float*)alloc((size_t)NCHUNK * BB * 4);
  float* rowpart_i = (float*)alloc((size_t)NCHUNK * BB * 4);

  pcount_kernel<<<nbp, 256, 0, stream>>>(edge_src, bcnt, E2, nbu, nbp);
  pscan_kernel<<<NRANGE, 256, 0, stream>>>(bcnt, boff, rtot, nbp);
  pscatter_kernel<<<nbp, 512, 0, stream>>>(edge_src, edge_dst, boff, rtot, binned,
                                           E2, nbu, nbp);
  place_kernel<<<NRANGE, 512, 0, stream>>>(binned, rtot, row_ptr, counts, csr_dst,
                                           user_table, item_table, y_init, E2);
  const int spmm_waves = NNODE / 4 + 1;         // 4 rows per wave + dummy-row wave
  const int spmm_blocks = (spmm_waves + 3) / 4; // 4 waves per 256-thread block
  spmm_kernel<<<spmm_blocks, 256, 0, stream>>>(y_init, row_ptr, csr_dst, counts,
                                               noise + (size_t)0 * NNODE * DDIM, yb0);
  spmm_kernel<<<spmm_blocks, 256, 0, stream>>>(yb0, row_ptr, csr_dst, counts,
                                               noise + (size_t)1 * NNODE * DDIM, yb1);
  spmm_kernel<<<spmm_blocks, 256, 0, stream>>>(yb1, row_ptr, csr_dst, counts,
                                               noise + (size_t)2 * NNODE * DDIM, yb2);
  batch_kernel<<<BB / 4, 256, 0, stream>>>(yb0, yb1, yb2, user_table, item_table, counts,
                                           user, positive, negative,
                                           z1u, z2u, z1i, z2i, pos_u, pos_i, sp_arr, rr_arr);
  dim3 ig(NCHUNK, BB / 64, 2);   // 4 chunks x 64 blocks.y (4 i-groups each) x {u,i}
  infonce_kernel<<<ig, 256, 0, stream>>>(z1u, z2u, z1i, z2i, rowpart_u, rowpart_i);
  finalize_kernel<<<1, 256, 0, stream>>>(rowpart_u, pos_u, rowpart_i, pos_i,
                                         sp_arr, rr_arr, (float*)d_out);
}